// Round 12
// baseline (422.756 us; speedup 1.0000x reference)
//
#include <hip/hip_runtime.h>

#define D_MODEL 1024
#define N_HEADS 16
#define D_K     64
#define BATCH   4
#define SEQ     2048
#define MROWS   (BATCH * SEQ)          // 8192
// Q pre-scale: (1/sqrt(64)) * log2(e) so attn uses raw exp2
#define QSCALE  0.18033688011112042f

typedef __bf16 bf16x8 __attribute__((ext_vector_type(8)));
typedef float  f32x4  __attribute__((ext_vector_type(4)));
typedef float  f32x16 __attribute__((ext_vector_type(16)));
typedef unsigned short ushort8 __attribute__((ext_vector_type(8)));
typedef unsigned short ushort4v __attribute__((ext_vector_type(4)));

#if __has_builtin(__builtin_amdgcn_exp2f)
#define EXP2F(x) __builtin_amdgcn_exp2f(x)
#else
#define EXP2F(x) exp2f(x)
#endif

// v_cvt_pk_bf16_f32: d.lo = bf16(a), d.hi = bf16(b)  (RNE)
#define CVT_PK_BF16(d, a, b) \
    asm("v_cvt_pk_bf16_f32 %0, %1, %2" : "=v"(d) : "v"(a), "v"(b))
// v_permlane32_swap_b32 a, b: a[32:63] <-> b[0:31]
#define PERMSWAP(a, b) \
    asm("v_permlane32_swap_b32 %0, %1" : "+v"(a), "+v"(b))
// compiler-only memory fence (pins issue order / blocks hoisting)
#define CFENCE()   asm volatile("" ::: "memory")

__device__ inline unsigned short f2bf(float f) {
    union { float f; unsigned int u; } v; v.f = f;
    unsigned int u = v.u;
    unsigned int r = (u + 0x7fffu + ((u >> 16) & 1u)) >> 16;
    return (unsigned short)r;
}

__device__ inline void load_lds16(const void* g, void* l) {
    __builtin_amdgcn_global_load_lds(
        (const __attribute__((address_space(1))) unsigned int*)g,
        (__attribute__((address_space(3))) unsigned int*)l, 16, 0, 0);
}

// ---------------- prep: weights fp32 [K][N] -> bf16 [N][K] ----------------
__global__ __launch_bounds__(256) void wprep(const float* __restrict__ Wq,
                                             const float* __restrict__ Wk,
                                             const float* __restrict__ Wv,
                                             const float* __restrict__ Wo,
                                             unsigned short* __restrict__ wt) {
    __shared__ __align__(16) unsigned short t[64][65];
    int w  = blockIdx.z;
    const float* W = (w == 0) ? Wq : (w == 1) ? Wk : (w == 2) ? Wv : Wo;
    int k0 = blockIdx.x * 64, n0 = blockIdx.y * 64;
    int tid = threadIdx.x;
    int nl = tid & 63, kq = tid >> 6;
#pragma unroll
    for (int i = 0; i < 16; i++) {
        int kl = kq * 16 + i;
        t[kl][nl] = f2bf(W[(size_t)(k0 + kl) * D_MODEL + n0 + nl]);
    }
    __syncthreads();
    unsigned short* out = wt + (size_t)w * D_MODEL * D_MODEL;
#pragma unroll
    for (int p = 0; p < 2; p++) {
        int nrow = p * 32 + (tid >> 3);
        int c8   = (tid & 7) * 8;
        ushort8 o;
#pragma unroll
        for (int j = 0; j < 8; j++) o[j] = t[c8 + j][nrow];
        *reinterpret_cast<ushort8*>(out + (size_t)(n0 + nrow) * D_MODEL + k0 + c8) = o;
    }
}

// ---------------- prep: x fp32 -> bf16 ----------------
__global__ __launch_bounds__(256) void xprep(const float4* __restrict__ x,
                                             unsigned short* __restrict__ xb) {
    int i = blockIdx.x * 256 + threadIdx.x;
    float4 v = x[i];
    ushort4v o;
    o[0] = f2bf(v.x); o[1] = f2bf(v.y); o[2] = f2bf(v.z); o[3] = f2bf(v.w);
    *reinterpret_cast<ushort4v*>(xb + (size_t)i * 4) = o;
}

// ---------------- prep: mask int32 -> bitmask (bit=1 means masked) --------
__global__ __launch_bounds__(256) void mprep(const int* __restrict__ mask,
                                             unsigned long long* __restrict__ mb) {
    int row = blockIdx.x;
    int tid = threadIdx.x;
    int wv  = tid >> 6;
#pragma unroll
    for (int w = 0; w < 8; w++) {
        int col = w * 256 + tid;
        int mval = mask[(size_t)row * SEQ + col];
        unsigned long long bits = __ballot(mval != 0);
        if ((tid & 63) == 0) mb[(size_t)row * 32 + w * 4 + wv] = bits;
    }
}

// ============ fused QKV GEMM: m97 structure, M=8192 N=3072 K=1024 =========
// Round-6 form (proven best): T1 XCD swizzle, single-buffer 2-barrier loop.
__global__ __launch_bounds__(256) void qkv_gemm(const unsigned short* __restrict__ xb,
                                                const unsigned short* __restrict__ wt,
                                                const float* __restrict__ bq,
                                                const float* __restrict__ bk,
                                                const float* __restrict__ bvv,
                                                unsigned short* __restrict__ qb,
                                                unsigned short* __restrict__ kb,
                                                unsigned short* __restrict__ vt) {
    __shared__ __align__(16) unsigned short lds_a[128 * 32];
    __shared__ __align__(16) unsigned short lds_b[128 * 32];
    int tid = threadIdx.x;
    int wave = tid >> 6, lane = tid & 63;
    int c = lane & 15, g = lane >> 4;
    int wave_m = (wave & 1) * 64, wave_n = (wave >> 1) * 64;
    int wg = blockIdx.x;
    int swz = (wg & 7) * 192 + (wg >> 3);      // bijective: 1536 % 8 == 0
    int nblk = (swz % 24) * 128, mblk = (swz / 24) * 128;

    int oct0 = wave * 128 + lane, oct1 = oct0 + 64;
    int ra0 = oct0 >> 2, ga0 = ((oct0 & 3) ^ (ra0 & 3)) * 8;
    int ra1 = oct1 >> 2, ga1 = ((oct1 & 3) ^ (ra1 & 3)) * 8;
    const unsigned short* pa0 = xb + (size_t)(mblk + ra0) * D_MODEL + ga0;
    const unsigned short* pa1 = xb + (size_t)(mblk + ra1) * D_MODEL + ga1;
    const unsigned short* pb0 = wt + (size_t)(nblk + ra0) * D_MODEL + ga0;
    const unsigned short* pb1 = wt + (size_t)(nblk + ra1) * D_MODEL + ga1;
    unsigned short* la0 = lds_a + wave * 1024;
    unsigned short* la1 = la0 + 512;
    unsigned short* lb0 = lds_b + wave * 1024;
    unsigned short* lb1 = lb0 + 512;

    int aoff[4], boff[4];
#pragma unroll
    for (int mi = 0; mi < 4; mi++) {
        int row = wave_m + mi * 16 + c;
        aoff[mi] = (row * 4 + (g ^ (row & 3))) * 16;
    }
#pragma unroll
    for (int ni = 0; ni < 4; ni++) {
        int row = wave_n + ni * 16 + c;
        boff[ni] = (row * 4 + (g ^ (row & 3))) * 16;
    }

    f32x4 acc[4][4];
#pragma unroll
    for (int mi = 0; mi < 4; mi++)
#pragma unroll
        for (int ni = 0; ni < 4; ni++) acc[mi][ni] = f32x4{0.f, 0.f, 0.f, 0.f};

    for (int k0 = 0; k0 < D_MODEL; k0 += 32) {
        load_lds16(pa0 + k0, la0);
        load_lds16(pa1 + k0, la1);
        load_lds16(pb0 + k0, lb0);
        load_lds16(pb1 + k0, lb1);
        __syncthreads();
        bf16x8 af[4], bfr[4];
#pragma unroll
        for (int mi = 0; mi < 4; mi++)
            af[mi] = *reinterpret_cast<const bf16x8*>(reinterpret_cast<const char*>(lds_a) + aoff[mi]);
#pragma unroll
        for (int ni = 0; ni < 4; ni++)
            bfr[ni] = *reinterpret_cast<const bf16x8*>(reinterpret_cast<const char*>(lds_b) + boff[ni]);
#pragma unroll
        for (int mi = 0; mi < 4; mi++)
#pragma unroll
            for (int ni = 0; ni < 4; ni++)
                acc[mi][ni] = __builtin_amdgcn_mfma_f32_16x16x32_bf16(af[mi], bfr[ni], acc[mi][ni], 0, 0, 0);
        __syncthreads();
    }

    int nb = nblk + wave_n;
    int wsel = nb >> 10;
    int h = (nb >> 6) & 15;
    int dk0 = nb & 63;
    int mglob = mblk + wave_m;
    int b = mglob >> 11;
    int s0 = mglob & (SEQ - 1);
    size_t bh = (size_t)(b * N_HEADS + h);
    const float* bias = (wsel == 0) ? bq : (wsel == 1) ? bk : bvv;
    int nn = nb & (D_MODEL - 1);
    float bval[4];
#pragma unroll
    for (int ni = 0; ni < 4; ni++) bval[ni] = bias[nn + ni * 16 + c];
    float oscale = (wsel == 0) ? QSCALE : 1.0f;

    if (wsel < 2) {
        unsigned short* outp = wsel ? kb : qb;
#pragma unroll
        for (int mi = 0; mi < 4; mi++)
#pragma unroll
            for (int ni = 0; ni < 4; ni++) {
                int dk = dk0 + ni * 16 + c;
#pragma unroll
                for (int r = 0; r < 4; r++) {
                    int s = s0 + mi * 16 + g * 4 + r;
                    outp[(bh * SEQ + s) * 64 + dk] = f2bf((acc[mi][ni][r] + bval[ni]) * oscale);
                }
            }
    } else {
#pragma unroll
        for (int mi = 0; mi < 4; mi++)
#pragma unroll
            for (int ni = 0; ni < 4; ni++) {
                int dk = dk0 + ni * 16 + c;
                int s = s0 + mi * 16 + g * 4;
                ushort4v o;
#pragma unroll
                for (int r = 0; r < 4; r++) o[r] = f2bf(acc[mi][ni][r] + bval[ni]);
                *reinterpret_cast<ushort4v*>(vt + (bh * 64 + dk) * SEQ + s) = o;
            }
    }
}

// ==== flash attention v15: LDS-FREE main loop (direct-L2 fragments) =======
// Cycle accounting of v11 (m134 model): 32 ds_read_b128 + glds + 4.3M
// conflicts/dispatch ~= 550+ LDS-port cyc per pair-iter -> port-bound, and
// K/V are L2-resident with row-contiguous 16B MFMA A-fragments. So: load
// K/V fragments DIRECTLY from L2 (guide common-mistake #7, m169 +26%).
// K reg-double-buffered (prefetch 1 iter ahead); V loaded per-s just
// before PV (softmax covers L2 latency); masks prefetched. No ds_read, no
// glds, no barriers in the loop. LDS (16KB) only for the epilogue bounce.
__global__ __launch_bounds__(128, 2) void attn(const unsigned short* __restrict__ qb,
                                               const unsigned short* __restrict__ kb,
                                               const unsigned short* __restrict__ vt,
                                               const unsigned long long* __restrict__ mb,
                                               unsigned short* __restrict__ ctx) {
    __shared__ __align__(16) unsigned char smem[16384];   // epilogue only

    int tid = threadIdx.x;
    int wave = tid >> 6, lane = tid & 63;
    int q31 = lane & 31, hi = lane >> 5;
    int bid = blockIdx.x;
    int swz = (bid & 7) * 128 + (bid >> 3);    // bijective: 1024 % 8 == 0
    int bh = swz >> 4;
    int q0 = (swz & 15) * 128 + wave * 64;
    int b = bh >> 4, h = bh & 15;
    const unsigned short* qbase = qb + (size_t)bh * SEQ * 64;
    const unsigned short* kbase = kb + (size_t)bh * SEQ * 64;
    const unsigned short* vbase = vt + (size_t)bh * 64 * SEQ;
    const unsigned long long* mp0 = mb + ((size_t)b * SEQ + q0 + q31) * 32;
    const unsigned long long* mp1 = mp0 + 1024;   // +32 rows * 32 words

    // Q B-frags for both tiles: chunk c covers dk = 16c + 8hi + (0..7)
    bf16x8 qf[2][4];
#pragma unroll
    for (int t = 0; t < 2; t++) {
        const unsigned short* qr = qbase + (size_t)(q0 + 32 * t + q31) * 64 + hi * 8;
#pragma unroll
        for (int c = 0; c < 4; c++)
            qf[t][c] = *reinterpret_cast<const bf16x8*>(qr + c * 16);
    }

    // K fragment pointers: frag (s,c) = K[it*64 + 32s + q31][dk 16c+8hi ..+8]
    const unsigned short* kpp[2];
    kpp[0] = kbase + (size_t)(q31) * 64 + hi * 8;
    kpp[1] = kbase + (size_t)(32 + q31) * 64 + hi * 8;
    // V fragment pointers: frag (so,c) = V[32so + q31][key it*64 + 16c+8hi ..+8]
    const unsigned short* vp[2];
    vp[0] = vbase + (size_t)(q31) * SEQ + hi * 8;
    vp[1] = vbase + (size_t)(32 + q31) * SEQ + hi * 8;

    float lsum[2] = {0.f, 0.f};
    f32x16 po[2][2];
#pragma unroll
    for (int i = 0; i < 16; i++) {
        po[0][0][i] = 0.f; po[0][1][i] = 0.f;
        po[1][0][i] = 0.f; po[1][1][i] = 0.f;
    }

    union PF { uint4 u; bf16x8 v; };

    // per-subtile compute: QK^T -> masked exp2 -> in-reg P frags -> PV
    unsigned long long w64c[2];
    auto proc = [&](int s, bf16x8 (&kc)[2][4], bf16x8 (&vf)[2][2]) {
        f32x16 sq[2];
#pragma unroll
        for (int i = 0; i < 16; i++) { sq[0][i] = 0.f; sq[1][i] = 0.f; }
        __builtin_amdgcn_s_setprio(1);
#pragma unroll
        for (int c = 0; c < 4; c++) {
            sq[0] = __builtin_amdgcn_mfma_f32_32x32x16_bf16(kc[s][c], qf[0][c], sq[0], 0, 0, 0);
            sq[1] = __builtin_amdgcn_mfma_f32_32x32x16_bf16(kc[s][c], qf[1][c], sq[1], 0, 0, 0);
        }
        __builtin_amdgcn_s_setprio(0);
        PF pf[2][2];   // [t][cp]
#pragma unroll
        for (int t = 0; t < 2; t++) {
            unsigned int wt_ = ~(unsigned int)(w64c[t] >> (32 * s));   // bit=1 -> keep
            float pm[16];
#pragma unroll
            for (int j = 0; j < 4; j++) {
                unsigned int nj = wt_ >> (8 * j + 4 * hi);
#pragma unroll
                for (int e = 0; e < 4; e++) {
                    float p = EXP2F(sq[t][4 * j + e]);
                    unsigned int m = (unsigned int)((int)(nj << (31 - e)) >> 31);
                    unsigned int pu = __float_as_uint(p) & m;
                    pm[4 * j + e] = __uint_as_float(pu);
                    lsum[t] += __uint_as_float(pu);
                }
            }
            unsigned int w[8];
#pragma unroll
            for (int j = 0; j < 4; j++) {
                CVT_PK_BF16(w[2 * j],     pm[4 * j + 0], pm[4 * j + 1]);
                CVT_PK_BF16(w[2 * j + 1], pm[4 * j + 2], pm[4 * j + 3]);
            }
            PERMSWAP(w[0], w[2]); PERMSWAP(w[1], w[3]);   // cp=0
            PERMSWAP(w[4], w[6]); PERMSWAP(w[5], w[7]);   // cp=1
            pf[t][0].u = uint4{w[0], w[1], w[2], w[3]};
            pf[t][1].u = uint4{w[4], w[5], w[6], w[7]};
        }
        __builtin_amdgcn_s_setprio(1);
#pragma unroll
        for (int cp = 0; cp < 2; cp++)
#pragma unroll
            for (int so = 0; so < 2; so++) {
                po[0][so] = __builtin_amdgcn_mfma_f32_32x32x16_bf16(vf[so][cp], pf[0][cp].v, po[0][so], 0, 0, 0);
                po[1][so] = __builtin_amdgcn_mfma_f32_32x32x16_bf16(vf[so][cp], pf[1][cp].v, po[1][so], 0, 0, 0);
            }
        __builtin_amdgcn_s_setprio(0);
    };

    // one 64-key step: kc = current K frags, kn <- prefetch next
    unsigned long long mnx0 = mp0[0], mnx1 = mp1[0];
    bf16x8 kA[2][4], kB[2][4];
#pragma unroll
    for (int s = 0; s < 2; s++)
#pragma unroll
        for (int c = 0; c < 4; c++)
            kA[s][c] = *reinterpret_cast<const bf16x8*>(kpp[s] + 16 * c);
    kpp[0] += 4096; kpp[1] += 4096;

    auto body = [&](bf16x8 (&kc)[2][4], bf16x8 (&kn)[2][4], int it) {
        w64c[0] = mnx0; w64c[1] = mnx1;
        int itn = (it + 1 < 32) ? it + 1 : it;   // clamp (redundant last)
        // V frags for s=0 (c = 0,1) — oldest in queue, PV(s=0) waits past nxt loads
        bf16x8 vf0[2][2];
#pragma unroll
        for (int so = 0; so < 2; so++)
#pragma unroll
            for (int cp = 0; cp < 2; cp++)
                vf0[so][cp] = *reinterpret_cast<const bf16x8*>(vp[so] + 16 * cp);
        CFENCE();
        // next-iter prefetch: masks then K frags (dangling last-iter K read
        // lands in the adjacent ws region — allocated, unused)
        mnx0 = mp0[itn]; mnx1 = mp1[itn];
#pragma unroll
        for (int s = 0; s < 2; s++)
#pragma unroll
            for (int c = 0; c < 4; c++)
                kn[s][c] = *reinterpret_cast<const bf16x8*>(kpp[s] + 16 * c);
        kpp[0] += 4096; kpp[1] += 4096;
        CFENCE();
        proc(0, kc, vf0);
        // V frags for s=1 (c = 2,3) — issued ~a softmax-phase before use
        bf16x8 vf1[2][2];
#pragma unroll
        for (int so = 0; so < 2; so++)
#pragma unroll
            for (int cp = 0; cp < 2; cp++)
                vf1[so][cp] = *reinterpret_cast<const bf16x8*>(vp[so] + 32 + 16 * cp);
        proc(1, kc, vf1);
        vp[0] += 64; vp[1] += 64;
    };

#pragma unroll 1
    for (int i2 = 0; i2 < 16; i2++) {
        body(kA, kB, 2 * i2);
        body(kB, kA, 2 * i2 + 1);
    }

    // finish row sums: partner (lane^32) holds the complementary key halves
    float inv[2];
#pragma unroll
    for (int t = 0; t < 2; t++) {
        lsum[t] += __shfl_xor(lsum[t], 32);
        inv[t] = 1.f / lsum[t];
    }

    // epilogue: normalize O^T (dk = 32so + 8j + 4hi + e), bounce via LDS
    // (wave-private 8KB region; no barrier needed)
    unsigned int* ob = (unsigned int*)(smem + wave * 8192);
    int csw = 4 * (q31 & 7);
#pragma unroll
    for (int t = 0; t < 2; t++) {
        unsigned int* obr = ob + (32 * t + q31) * 32;
#pragma unroll
        for (int so = 0; so < 2; so++)
#pragma unroll
            for (int j = 0; j < 4; j++) {
                unsigned int w0 = (unsigned int)f2bf(po[t][so][4 * j + 0] * inv[t])
                                | ((unsigned int)f2bf(po[t][so][4 * j + 1] * inv[t]) << 16);
                unsigned int w1 = (unsigned int)f2bf(po[t][so][4 * j + 2] * inv[t])
                                | ((unsigned int)f2bf(po[t][so][4 * j + 3] * inv[t]) << 16);
                int d = (16 * so + 4 * j + 2 * hi) ^ csw;
                uint2 u; u.x = w0; u.y = w1;
                *reinterpret_cast<uint2*>(obr + d) = u;
            }
    }
    __builtin_amdgcn_s_waitcnt(0);   // drain own ds_writes (wave-private region)
    size_t crow = (size_t)b * SEQ + q0;
    int o = lane & 7, rl = lane >> 3;
#pragma unroll
    for (int i = 0; i < 8; i++) {
        int r = 8 * i + rl;
        uint4 v = *reinterpret_cast<const uint4*>(ob + r * 32 + 4 * (o ^ (r & 7)));
        *reinterpret_cast<uint4*>(ctx + (crow + r) * D_MODEL + h * 64 + o * 8) = v;
    }
}

// ============ output projection: m97 structure, M=8192 N=1024 K=1024 ======
// Round-6 form (proven): T1 swizzle, single-buffer 2-barrier loop.
__global__ __launch_bounds__(256) void oproj(const unsigned short* __restrict__ ctx,
                                             const unsigned short* __restrict__ wt,
                                             const float* __restrict__ bo,
                                             float* __restrict__ out) {
    __shared__ __align__(16) unsigned short lds_a[128 * 32];
    __shared__ __align__(16) unsigned short lds_b[128 * 32];
    int tid = threadIdx.x;
    int wave = tid >> 6, lane = tid & 63;
    int c = lane & 15, g = lane >> 4;
    int wave_m = (wave & 1) * 64, wave_n = (wave >> 1) * 64;
    int wg = blockIdx.x;
    int swz = (wg & 7) * 64 + (wg >> 3);       // bijective: 512 % 8 == 0
    int nblk = (swz & 7) * 128, mblk = (swz >> 3) * 128;
    const unsigned short* wo = wt + (size_t)3 * D_MODEL * D_MODEL;

    int oct0 = wave * 128 + lane, oct1 = oct0 + 64;
    int ra0 = oct0 >> 2, ga0 = ((oct0 & 3) ^ (ra0 & 3)) * 8;
    int ra1 = oct1 >> 2, ga1 = ((oct1 & 3) ^ (ra1 & 3)) * 8;
    const unsigned short* pa0 = ctx + (size_t)(mblk + ra0) * D_MODEL + ga0;
    const unsigned short* pa1 = ctx + (size_t)(mblk + ra1) * D_MODEL + ga1;
    const unsigned short* pb0 = wo + (size_t)(nblk + ra0) * D_MODEL + ga0;
    const unsigned short* pb1 = wo + (size_t)(nblk + ra1) * D_MODEL + ga1;
    unsigned short* la0 = lds_a + wave * 1024;
    unsigned short* la1 = la0 + 512;
    unsigned short* lb0 = lds_b + wave * 1024;
    unsigned short* lb1 = lb0 + 512;

    int aoff[4], boff[4];
#pragma unroll
    for (int mi = 0; mi < 4; mi++) {
        int row = wave_m + mi * 16 + c;
        aoff[mi] = (row * 4 + (g ^ (row & 3))) * 16;
    }
#pragma unroll
    for (int ni = 0; ni < 4; ni++) {
        int row = wave_n + ni * 16 + c;
        boff[ni] = (row * 4 + (g ^ (row & 3))) * 16;
    }

    f32x4 acc[4][4];
#pragma unroll
    for (int mi = 0; mi < 4; mi++)
#pragma unroll
        for (int ni = 0; ni < 4; ni++) acc[mi][ni] = f32x4{0.f, 0.f, 0.f, 0.f};

    for (int k0 = 0; k0 < D_MODEL; k0 += 32) {
        load_lds16(pa0 + k0, la0);
        load_lds16(pa1 + k0, la1);
        load_lds16(pb0 + k0, lb0);
        load_lds16(pb1 + k0, lb1);
        __syncthreads();
        bf16x8 af[4], bfr[4];
#pragma unroll
        for (int mi = 0; mi < 4; mi++)
            af[mi] = *reinterpret_cast<const bf16x8*>(reinterpret_cast<const char*>(lds_a) + aoff[mi]);
#pragma unroll
        for (int ni = 0; ni < 4; ni++)
            bfr[ni] = *reinterpret_cast<const bf16x8*>(reinterpret_cast<const char*>(lds_b) + boff[ni]);
#pragma unroll
        for (int mi = 0; mi < 4; mi++)
#pragma unroll
            for (int ni = 0; ni < 4; ni++)
                acc[mi][ni] = __builtin_amdgcn_mfma_f32_16x16x32_bf16(af[mi], bfr[ni], acc[mi][ni], 0, 0, 0);
        __syncthreads();
    }

    float bval[4];
#pragma unroll
    for (int ni = 0; ni < 4; ni++) bval[ni] = bo[nblk + wave_n + ni * 16 + c];
#pragma unroll
    for (int mi = 0; mi < 4; mi++)
#pragma unroll
        for (int ni = 0; ni < 4; ni++) {
            int n = nblk + wave_n + ni * 16 + c;
#pragma unroll
            for (int r = 0; r < 4; r++) {
                int m = mblk + wave_m + mi * 16 + g * 4 + r;
                out[(size_t)m * D_MODEL + n] = acc[mi][ni][r] + bval[ni];
            }
        }
}

extern "C" void kernel_launch(void* const* d_in, const int* in_sizes, int n_in,
                              void* d_out, int out_size, void* d_ws, size_t ws_size,
                              hipStream_t stream) {
    const float* x    = (const float*)d_in[0];
    const int*   mask = (const int*)d_in[1];
    const float* Wq = (const float*)d_in[2];
    const float* bq = (const float*)d_in[3];
    const float* Wk = (const float*)d_in[4];
    const float* bk = (const float*)d_in[5];
    const float* Wv = (const float*)d_in[6];
    const float* bv = (const float*)d_in[7];
    const float* Wo = (const float*)d_in[8];
    const float* bo = (const float*)d_in[9];
    float* out = (float*)d_out;

    char* ws = (char*)d_ws;
    const size_t MB = 1024 * 1024;
    unsigned short* wt  = (unsigned short*)(ws + 0 * MB);
    unsigned short* xb  = (unsigned short*)(ws + 8 * MB);
    unsigned short* qb  = (unsigned short*)(ws + 24 * MB);
    unsigned short* kb  = (unsigned short*)(ws + 40 * MB);
    unsigned short* vt  = (unsigned short*)(ws + 56 * MB);
    unsigned short* ctx = (unsigned short*)(ws + 72 * MB);
    unsigned long long* mb = (unsigned long long*)(ws + 88 * MB);

    wprep<<<dim3(16, 16, 4), 256, 0, stream>>>(Wq, Wk, Wv, Wo, wt);
    xprep<<<dim3(MROWS * D_MODEL / 4 / 256), 256, 0, stream>>>((const float4*)x, xb);
    mprep<<<dim3(MROWS), 256, 0, stream>>>(mask, mb);
    qkv_gemm<<<dim3(1536), 256, 0, stream>>>(xb, wt, bq, bk, bv, qb, kb, vt);
    attn<<<dim3(1024), 128, 0, stream>>>(qb, kb, vt, mb, ctx);
    oproj<<<dim3(512), 256, 0, stream>>>(ctx, wt, bo, out);
}

// Round 13
// 406.072 us; speedup vs baseline: 1.0411x; 1.0411x over previous
//
#include <hip/hip_runtime.h>

#define D_MODEL 1024
#define N_HEADS 16
#define D_K     64
#define BATCH   4
#define SEQ     2048
#define MROWS   (BATCH * SEQ)          // 8192
// Q pre-scale: (1/sqrt(64)) * log2(e) so attn uses raw exp2
#define QSCALE  0.18033688011112042f

typedef __bf16 bf16x8 __attribute__((ext_vector_type(8)));
typedef float  f32x4  __attribute__((ext_vector_type(4)));
typedef float  f32x16 __attribute__((ext_vector_type(16)));
typedef unsigned short ushort8 __attribute__((ext_vector_type(8)));
typedef unsigned short ushort4v __attribute__((ext_vector_type(4)));

#if __has_builtin(__builtin_amdgcn_exp2f)
#define EXP2F(x) __builtin_amdgcn_exp2f(x)
#else
#define EXP2F(x) exp2f(x)
#endif

// v_cvt_pk_bf16_f32: d.lo = bf16(a), d.hi = bf16(b)  (RNE)
#define CVT_PK_BF16(d, a, b) \
    asm("v_cvt_pk_bf16_f32 %0, %1, %2" : "=v"(d) : "v"(a), "v"(b))
// v_permlane32_swap_b32 a, b: a[32:63] <-> b[0:31]
#define PERMSWAP(a, b) \
    asm("v_permlane32_swap_b32 %0, %1" : "+v"(a), "+v"(b))
// compiler-only memory fence (pins issue order / blocks hoisting)
#define CFENCE()   asm volatile("" ::: "memory")

__device__ inline unsigned short f2bf(float f) {
    union { float f; unsigned int u; } v; v.f = f;
    unsigned int u = v.u;
    unsigned int r = (u + 0x7fffu + ((u >> 16) & 1u)) >> 16;
    return (unsigned short)r;
}

__device__ inline void load_lds16(const void* g, void* l) {
    __builtin_amdgcn_global_load_lds(
        (const __attribute__((address_space(1))) unsigned int*)g,
        (__attribute__((address_space(3))) unsigned int*)l, 16, 0, 0);
}

// ---------------- prep: weights fp32 [K][N] -> bf16 [N][K] ----------------
__global__ __launch_bounds__(256) void wprep(const float* __restrict__ Wq,
                                             const float* __restrict__ Wk,
                                             const float* __restrict__ Wv,
                                             const float* __restrict__ Wo,
                                             unsigned short* __restrict__ wt) {
    __shared__ __align__(16) unsigned short t[64][65];
    int w  = blockIdx.z;
    const float* W = (w == 0) ? Wq : (w == 1) ? Wk : (w == 2) ? Wv : Wo;
    int k0 = blockIdx.x * 64, n0 = blockIdx.y * 64;
    int tid = threadIdx.x;
    int nl = tid & 63, kq = tid >> 6;
#pragma unroll
    for (int i = 0; i < 16; i++) {
        int kl = kq * 16 + i;
        t[kl][nl] = f2bf(W[(size_t)(k0 + kl) * D_MODEL + n0 + nl]);
    }
    __syncthreads();
    unsigned short* out = wt + (size_t)w * D_MODEL * D_MODEL;
#pragma unroll
    for (int p = 0; p < 2; p++) {
        int nrow = p * 32 + (tid >> 3);
        int c8   = (tid & 7) * 8;
        ushort8 o;
#pragma unroll
        for (int j = 0; j < 8; j++) o[j] = t[c8 + j][nrow];
        *reinterpret_cast<ushort8*>(out + (size_t)(n0 + nrow) * D_MODEL + k0 + c8) = o;
    }
}

// ---------------- prep: x fp32 -> bf16 ----------------
__global__ __launch_bounds__(256) void xprep(const float4* __restrict__ x,
                                             unsigned short* __restrict__ xb) {
    int i = blockIdx.x * 256 + threadIdx.x;
    float4 v = x[i];
    ushort4v o;
    o[0] = f2bf(v.x); o[1] = f2bf(v.y); o[2] = f2bf(v.z); o[3] = f2bf(v.w);
    *reinterpret_cast<ushort4v*>(xb + (size_t)i * 4) = o;
}

// ---------------- prep: mask int32 -> bitmask (bit=1 means masked) --------
__global__ __launch_bounds__(256) void mprep(const int* __restrict__ mask,
                                             unsigned long long* __restrict__ mb) {
    int row = blockIdx.x;
    int tid = threadIdx.x;
    int wv  = tid >> 6;
#pragma unroll
    for (int w = 0; w < 8; w++) {
        int col = w * 256 + tid;
        int mval = mask[(size_t)row * SEQ + col];
        unsigned long long bits = __ballot(mval != 0);
        if ((tid & 63) == 0) mb[(size_t)row * 32 + w * 4 + wv] = bits;
    }
}

// ============ fused QKV GEMM: m97 structure, M=8192 N=3072 K=1024 =========
// Round-6 form (proven best): T1 XCD swizzle, single-buffer 2-barrier loop.
__global__ __launch_bounds__(256) void qkv_gemm(const unsigned short* __restrict__ xb,
                                                const unsigned short* __restrict__ wt,
                                                const float* __restrict__ bq,
                                                const float* __restrict__ bk,
                                                const float* __restrict__ bvv,
                                                unsigned short* __restrict__ qb,
                                                unsigned short* __restrict__ kb,
                                                unsigned short* __restrict__ vt) {
    __shared__ __align__(16) unsigned short lds_a[128 * 32];
    __shared__ __align__(16) unsigned short lds_b[128 * 32];
    int tid = threadIdx.x;
    int wave = tid >> 6, lane = tid & 63;
    int c = lane & 15, g = lane >> 4;
    int wave_m = (wave & 1) * 64, wave_n = (wave >> 1) * 64;
    int wg = blockIdx.x;
    int swz = (wg & 7) * 192 + (wg >> 3);      // bijective: 1536 % 8 == 0
    int nblk = (swz % 24) * 128, mblk = (swz / 24) * 128;

    int oct0 = wave * 128 + lane, oct1 = oct0 + 64;
    int ra0 = oct0 >> 2, ga0 = ((oct0 & 3) ^ (ra0 & 3)) * 8;
    int ra1 = oct1 >> 2, ga1 = ((oct1 & 3) ^ (ra1 & 3)) * 8;
    const unsigned short* pa0 = xb + (size_t)(mblk + ra0) * D_MODEL + ga0;
    const unsigned short* pa1 = xb + (size_t)(mblk + ra1) * D_MODEL + ga1;
    const unsigned short* pb0 = wt + (size_t)(nblk + ra0) * D_MODEL + ga0;
    const unsigned short* pb1 = wt + (size_t)(nblk + ra1) * D_MODEL + ga1;
    unsigned short* la0 = lds_a + wave * 1024;
    unsigned short* la1 = la0 + 512;
    unsigned short* lb0 = lds_b + wave * 1024;
    unsigned short* lb1 = lb0 + 512;

    int aoff[4], boff[4];
#pragma unroll
    for (int mi = 0; mi < 4; mi++) {
        int row = wave_m + mi * 16 + c;
        aoff[mi] = (row * 4 + (g ^ (row & 3))) * 16;
    }
#pragma unroll
    for (int ni = 0; ni < 4; ni++) {
        int row = wave_n + ni * 16 + c;
        boff[ni] = (row * 4 + (g ^ (row & 3))) * 16;
    }

    f32x4 acc[4][4];
#pragma unroll
    for (int mi = 0; mi < 4; mi++)
#pragma unroll
        for (int ni = 0; ni < 4; ni++) acc[mi][ni] = f32x4{0.f, 0.f, 0.f, 0.f};

    for (int k0 = 0; k0 < D_MODEL; k0 += 32) {
        load_lds16(pa0 + k0, la0);
        load_lds16(pa1 + k0, la1);
        load_lds16(pb0 + k0, lb0);
        load_lds16(pb1 + k0, lb1);
        __syncthreads();
        bf16x8 af[4], bfr[4];
#pragma unroll
        for (int mi = 0; mi < 4; mi++)
            af[mi] = *reinterpret_cast<const bf16x8*>(reinterpret_cast<const char*>(lds_a) + aoff[mi]);
#pragma unroll
        for (int ni = 0; ni < 4; ni++)
            bfr[ni] = *reinterpret_cast<const bf16x8*>(reinterpret_cast<const char*>(lds_b) + boff[ni]);
#pragma unroll
        for (int mi = 0; mi < 4; mi++)
#pragma unroll
            for (int ni = 0; ni < 4; ni++)
                acc[mi][ni] = __builtin_amdgcn_mfma_f32_16x16x32_bf16(af[mi], bfr[ni], acc[mi][ni], 0, 0, 0);
        __syncthreads();
    }

    int nb = nblk + wave_n;
    int wsel = nb >> 10;
    int h = (nb >> 6) & 15;
    int dk0 = nb & 63;
    int mglob = mblk + wave_m;
    int b = mglob >> 11;
    int s0 = mglob & (SEQ - 1);
    size_t bh = (size_t)(b * N_HEADS + h);
    const float* bias = (wsel == 0) ? bq : (wsel == 1) ? bk : bvv;
    int nn = nb & (D_MODEL - 1);
    float bval[4];
#pragma unroll
    for (int ni = 0; ni < 4; ni++) bval[ni] = bias[nn + ni * 16 + c];
    float oscale = (wsel == 0) ? QSCALE : 1.0f;

    if (wsel < 2) {
        unsigned short* outp = wsel ? kb : qb;
#pragma unroll
        for (int mi = 0; mi < 4; mi++)
#pragma unroll
            for (int ni = 0; ni < 4; ni++) {
                int dk = dk0 + ni * 16 + c;
#pragma unroll
                for (int r = 0; r < 4; r++) {
                    int s = s0 + mi * 16 + g * 4 + r;
                    outp[(bh * SEQ + s) * 64 + dk] = f2bf((acc[mi][ni][r] + bval[ni]) * oscale);
                }
            }
    } else {
#pragma unroll
        for (int mi = 0; mi < 4; mi++)
#pragma unroll
            for (int ni = 0; ni < 4; ni++) {
                int dk = dk0 + ni * 16 + c;
                int s = s0 + mi * 16 + g * 4;
                ushort4v o;
#pragma unroll
                for (int r = 0; r < 4; r++) o[r] = f2bf(acc[mi][ni][r] + bval[ni]);
                *reinterpret_cast<ushort4v*>(vt + (bh * 64 + dk) * SEQ + s) = o;
            }
    }
}

// ==== flash attention v16: LDS-free loop, rule-#20-clean (no lambdas) =====
// v15 post-mortem: conflicts 4.3M->131K proved the LDS-port theory, but the
// proc/body LAMBDAS (runtime `s` param + aliased array refs kA/kB) forced
// K-frag arrays into scratch: WRITE 16->43MB, VGPR stuck at 128, 176us.
// v16: identical math, but all fragments are individually-NAMED registers
// and the loop body is textual macro expansion — zero runtime indexing,
// zero aliasing. K reg-double-buffered; V loaded per-subtile; no ds_read,
// no glds, no barriers in the loop. LDS only for the epilogue bounce.
#define LD8(p) (*reinterpret_cast<const bf16x8*>(p))

#define PROC_T(SQ, W, S, LSUM, PF0, PF1)                                      \
    {                                                                         \
        unsigned int wt_ = ~(unsigned int)((W) >> (32 * (S)));                \
        float pm[16];                                                         \
        _Pragma("unroll") for (int j = 0; j < 4; j++) {                       \
            unsigned int nj = wt_ >> (8 * j + 4 * hi);                        \
            _Pragma("unroll") for (int e = 0; e < 4; e++) {                   \
                float p = EXP2F((SQ)[4 * j + e]);                             \
                unsigned int m_ = (unsigned int)((int)(nj << (31 - e)) >> 31);\
                unsigned int pu = __float_as_uint(p) & m_;                    \
                pm[4 * j + e] = __uint_as_float(pu);                          \
                LSUM += __uint_as_float(pu);                                  \
            }                                                                 \
        }                                                                     \
        unsigned int w_[8];                                                   \
        _Pragma("unroll") for (int j = 0; j < 4; j++) {                       \
            CVT_PK_BF16(w_[2 * j],     pm[4 * j + 0], pm[4 * j + 1]);         \
            CVT_PK_BF16(w_[2 * j + 1], pm[4 * j + 2], pm[4 * j + 3]);         \
        }                                                                     \
        PERMSWAP(w_[0], w_[2]); PERMSWAP(w_[1], w_[3]);                       \
        PERMSWAP(w_[4], w_[6]); PERMSWAP(w_[5], w_[7]);                       \
        PF0.u = uint4{w_[0], w_[1], w_[2], w_[3]};                            \
        PF1.u = uint4{w_[4], w_[5], w_[6], w_[7]};                            \
    }

// One 32-key subtile: QK^T (K frags K0..K3) -> masked exp2 -> in-reg P ->
// PV with V frags VA(so0,cp0) VB(so0,cp1) VC(so1,cp0) VD(so1,cp1).
#define PROC(S, K0, K1, K2, K3, VA, VB, VC, VD, W0, W1)                       \
    {                                                                         \
        f32x16 sq0, sq1;                                                      \
        _Pragma("unroll") for (int i_ = 0; i_ < 16; i_++) { sq0[i_] = 0.f; sq1[i_] = 0.f; } \
        __builtin_amdgcn_s_setprio(1);                                        \
        sq0 = __builtin_amdgcn_mfma_f32_32x32x16_bf16(K0, qf00, sq0, 0, 0, 0);\
        sq1 = __builtin_amdgcn_mfma_f32_32x32x16_bf16(K0, qf10, sq1, 0, 0, 0);\
        sq0 = __builtin_amdgcn_mfma_f32_32x32x16_bf16(K1, qf01, sq0, 0, 0, 0);\
        sq1 = __builtin_amdgcn_mfma_f32_32x32x16_bf16(K1, qf11, sq1, 0, 0, 0);\
        sq0 = __builtin_amdgcn_mfma_f32_32x32x16_bf16(K2, qf02, sq0, 0, 0, 0);\
        sq1 = __builtin_amdgcn_mfma_f32_32x32x16_bf16(K2, qf12, sq1, 0, 0, 0);\
        sq0 = __builtin_amdgcn_mfma_f32_32x32x16_bf16(K3, qf03, sq0, 0, 0, 0);\
        sq1 = __builtin_amdgcn_mfma_f32_32x32x16_bf16(K3, qf13, sq1, 0, 0, 0);\
        __builtin_amdgcn_s_setprio(0);                                        \
        PFu pf00_, pf01_, pf10_, pf11_;                                       \
        PROC_T(sq0, W0, S, lsum0, pf00_, pf01_)                               \
        PROC_T(sq1, W1, S, lsum1, pf10_, pf11_)                               \
        __builtin_amdgcn_s_setprio(1);                                        \
        po00 = __builtin_amdgcn_mfma_f32_32x32x16_bf16(VA, pf00_.v, po00, 0, 0, 0); \
        po01 = __builtin_amdgcn_mfma_f32_32x32x16_bf16(VC, pf00_.v, po01, 0, 0, 0); \
        po10 = __builtin_amdgcn_mfma_f32_32x32x16_bf16(VA, pf10_.v, po10, 0, 0, 0); \
        po11 = __builtin_amdgcn_mfma_f32_32x32x16_bf16(VC, pf10_.v, po11, 0, 0, 0); \
        po00 = __builtin_amdgcn_mfma_f32_32x32x16_bf16(VB, pf01_.v, po00, 0, 0, 0); \
        po01 = __builtin_amdgcn_mfma_f32_32x32x16_bf16(VD, pf01_.v, po01, 0, 0, 0); \
        po10 = __builtin_amdgcn_mfma_f32_32x32x16_bf16(VB, pf11_.v, po10, 0, 0, 0); \
        po11 = __builtin_amdgcn_mfma_f32_32x32x16_bf16(VD, pf11_.v, po11, 0, 0, 0); \
        __builtin_amdgcn_s_setprio(0);                                        \
    }

// One 64-key step: compute on KC##xx, prefetch next tile into KN##xx.
#define STEP(KC, KN, IT)                                                      \
    {                                                                         \
        unsigned long long w0c = mnx0, w1c = mnx1;                            \
        int itn_ = ((IT) + 1 < 32) ? (IT) + 1 : (IT);                         \
        bf16x8 va0 = LD8(vp0);      bf16x8 vb0 = LD8(vp0 + 16);               \
        bf16x8 vc0 = LD8(vp1);      bf16x8 vd0 = LD8(vp1 + 16);               \
        CFENCE();                                                             \
        mnx0 = mp0[itn_]; mnx1 = mp1[itn_];                                   \
        KN##00 = LD8(kp0);      KN##01 = LD8(kp0 + 16);                       \
        KN##02 = LD8(kp0 + 32); KN##03 = LD8(kp0 + 48);                       \
        KN##10 = LD8(kp1);      KN##11 = LD8(kp1 + 16);                       \
        KN##12 = LD8(kp1 + 32); KN##13 = LD8(kp1 + 48);                       \
        kp0 += 4096; kp1 += 4096;                                             \
        CFENCE();                                                             \
        PROC(0, KC##00, KC##01, KC##02, KC##03, va0, vb0, vc0, vd0, w0c, w1c) \
        bf16x8 va1 = LD8(vp0 + 32); bf16x8 vb1 = LD8(vp0 + 48);               \
        bf16x8 vc1 = LD8(vp1 + 32); bf16x8 vd1 = LD8(vp1 + 48);               \
        PROC(1, KC##10, KC##11, KC##12, KC##13, va1, vb1, vc1, vd1, w0c, w1c) \
        vp0 += 64; vp1 += 64;                                                 \
    }

__global__ __launch_bounds__(128, 2) void attn(const unsigned short* __restrict__ qb,
                                               const unsigned short* __restrict__ kb,
                                               const unsigned short* __restrict__ vt,
                                               const unsigned long long* __restrict__ mb,
                                               unsigned short* __restrict__ ctx) {
    __shared__ __align__(16) unsigned char smem[16384];   // epilogue only

    int tid = threadIdx.x;
    int wave = tid >> 6, lane = tid & 63;
    int q31 = lane & 31, hi = lane >> 5;
    int bid = blockIdx.x;
    int swz = (bid & 7) * 128 + (bid >> 3);    // bijective: 1024 % 8 == 0
    int bh = swz >> 4;
    int q0 = (swz & 15) * 128 + wave * 64;
    int b = bh >> 4, h = bh & 15;
    const unsigned short* qbase = qb + (size_t)bh * SEQ * 64;
    const unsigned short* kbase = kb + (size_t)bh * SEQ * 64;
    const unsigned short* vbase = vt + (size_t)bh * 64 * SEQ;
    const unsigned long long* mp0 = mb + ((size_t)b * SEQ + q0 + q31) * 32;
    const unsigned long long* mp1 = mp0 + 1024;   // +32 rows * 32 words

    // Q B-frags (named): qf<t><c>, chunk c covers dk = 16c + 8hi + (0..7)
    const unsigned short* qr0 = qbase + (size_t)(q0 + q31) * 64 + hi * 8;
    const unsigned short* qr1 = qbase + (size_t)(q0 + 32 + q31) * 64 + hi * 8;
    bf16x8 qf00 = LD8(qr0),      qf01 = LD8(qr0 + 16);
    bf16x8 qf02 = LD8(qr0 + 32), qf03 = LD8(qr0 + 48);
    bf16x8 qf10 = LD8(qr1),      qf11 = LD8(qr1 + 16);
    bf16x8 qf12 = LD8(qr1 + 32), qf13 = LD8(qr1 + 48);

    // K frag ptrs: frag (s,c) = K[it*64 + 32s + q31][dk 16c+8hi ..+8]
    const unsigned short* kp0 = kbase + (size_t)q31 * 64 + hi * 8;
    const unsigned short* kp1 = kbase + (size_t)(32 + q31) * 64 + hi * 8;
    // V frag ptrs: frag (so,*) = V[32so + q31][key it*64 + ... + 8hi ..+8]
    const unsigned short* vp0 = vbase + (size_t)q31 * SEQ + hi * 8;
    const unsigned short* vp1 = vbase + (size_t)(32 + q31) * SEQ + hi * 8;

    float lsum0 = 0.f, lsum1 = 0.f;
    f32x16 po00, po01, po10, po11;   // po<t><so>
#pragma unroll
    for (int i = 0; i < 16; i++) {
        po00[i] = 0.f; po01[i] = 0.f; po10[i] = 0.f; po11[i] = 0.f;
    }

    union PFu { uint4 u; bf16x8 v; };

    // prologue: masks + K tile 0 into kA
    unsigned long long mnx0 = mp0[0], mnx1 = mp1[0];
    bf16x8 kA00 = LD8(kp0),      kA01 = LD8(kp0 + 16);
    bf16x8 kA02 = LD8(kp0 + 32), kA03 = LD8(kp0 + 48);
    bf16x8 kA10 = LD8(kp1),      kA11 = LD8(kp1 + 16);
    bf16x8 kA12 = LD8(kp1 + 32), kA13 = LD8(kp1 + 48);
    bf16x8 kB00, kB01, kB02, kB03, kB10, kB11, kB12, kB13;
    kp0 += 4096; kp1 += 4096;

#pragma unroll 1
    for (int i2 = 0; i2 < 16; i2++) {
        STEP(kA, kB, 2 * i2)
        STEP(kB, kA, 2 * i2 + 1)
    }

    // finish row sums: partner (lane^32) holds the complementary key halves
    lsum0 += __shfl_xor(lsum0, 32);
    lsum1 += __shfl_xor(lsum1, 32);
    float inv0 = 1.f / lsum0, inv1 = 1.f / lsum1;

    // epilogue: normalize O^T (dk = 32so + 8j + 4hi + e), bounce via LDS
    // (wave-private 8KB region; no barrier needed)
    f32x16 poA[2][2];
    poA[0][0] = po00; poA[0][1] = po01; poA[1][0] = po10; poA[1][1] = po11;
    float invA[2] = {inv0, inv1};
    unsigned int* ob = (unsigned int*)(smem + wave * 8192);
    int csw = 4 * (q31 & 7);
#pragma unroll
    for (int t = 0; t < 2; t++) {
        unsigned int* obr = ob + (32 * t + q31) * 32;
#pragma unroll
        for (int so = 0; so < 2; so++)
#pragma unroll
            for (int j = 0; j < 4; j++) {
                unsigned int w0 = (unsigned int)f2bf(poA[t][so][4 * j + 0] * invA[t])
                                | ((unsigned int)f2bf(poA[t][so][4 * j + 1] * invA[t]) << 16);
                unsigned int w1 = (unsigned int)f2bf(poA[t][so][4 * j + 2] * invA[t])
                                | ((unsigned int)f2bf(poA[t][so][4 * j + 3] * invA[t]) << 16);
                int d = (16 * so + 4 * j + 2 * hi) ^ csw;
                uint2 u; u.x = w0; u.y = w1;
                *reinterpret_cast<uint2*>(obr + d) = u;
            }
    }
    __builtin_amdgcn_s_waitcnt(0);   // drain own ds_writes (wave-private region)
    size_t crow = (size_t)b * SEQ + q0;
    int o = lane & 7, rl = lane >> 3;
#pragma unroll
    for (int i = 0; i < 8; i++) {
        int r = 8 * i + rl;
        uint4 v = *reinterpret_cast<const uint4*>(ob + r * 32 + 4 * (o ^ (r & 7)));
        *reinterpret_cast<uint4*>(ctx + (crow + r) * D_MODEL + h * 64 + o * 8) = v;
    }
}

// ============ output projection: m97 structure, M=8192 N=1024 K=1024 ======
// Round-6 form (proven): T1 swizzle, single-buffer 2-barrier loop.
__global__ __launch_bounds__(256) void oproj(const unsigned short* __restrict__ ctx,
                                             const unsigned short* __restrict__ wt,
                                             const float* __restrict__ bo,
                                             float* __restrict__ out) {
    __shared__ __align__(16) unsigned short lds_a[128 * 32];
    __shared__ __align__(16) unsigned short lds_b[128 * 32];
    int tid = threadIdx.x;
    int wave = tid >> 6, lane = tid & 63;
    int c = lane & 15, g = lane >> 4;
    int wave_m = (wave & 1) * 64, wave_n = (wave >> 1) * 64;
    int wg = blockIdx.x;
    int swz = (wg & 7) * 64 + (wg >> 3);       // bijective: 512 % 8 == 0
    int nblk = (swz & 7) * 128, mblk = (swz >> 3) * 128;
    const unsigned short* wo = wt + (size_t)3 * D_MODEL * D_MODEL;

    int oct0 = wave * 128 + lane, oct1 = oct0 + 64;
    int ra0 = oct0 >> 2, ga0 = ((oct0 & 3) ^ (ra0 & 3)) * 8;
    int ra1 = oct1 >> 2, ga1 = ((oct1 & 3) ^ (ra1 & 3)) * 8;
    const unsigned short* pa0 = ctx + (size_t)(mblk + ra0) * D_MODEL + ga0;
    const unsigned short* pa1 = ctx + (size_t)(mblk + ra1) * D_MODEL + ga1;
    const unsigned short* pb0 = wo + (size_t)(nblk + ra0) * D_MODEL + ga0;
    const unsigned short* pb1 = wo + (size_t)(nblk + ra1) * D_MODEL + ga1;
    unsigned short* la0 = lds_a + wave * 1024;
    unsigned short* la1 = la0 + 512;
    unsigned short* lb0 = lds_b + wave * 1024;
    unsigned short* lb1 = lb0 + 512;

    int aoff[4], boff[4];
#pragma unroll
    for (int mi = 0; mi < 4; mi++) {
        int row = wave_m + mi * 16 + c;
        aoff[mi] = (row * 4 + (g ^ (row & 3))) * 16;
    }
#pragma unroll
    for (int ni = 0; ni < 4; ni++) {
        int row = wave_n + ni * 16 + c;
        boff[ni] = (row * 4 + (g ^ (row & 3))) * 16;
    }

    f32x4 acc[4][4];
#pragma unroll
    for (int mi = 0; mi < 4; mi++)
#pragma unroll
        for (int ni = 0; ni < 4; ni++) acc[mi][ni] = f32x4{0.f, 0.f, 0.f, 0.f};

    for (int k0 = 0; k0 < D_MODEL; k0 += 32) {
        load_lds16(pa0 + k0, la0);
        load_lds16(pa1 + k0, la1);
        load_lds16(pb0 + k0, lb0);
        load_lds16(pb1 + k0, lb1);
        __syncthreads();
        bf16x8 af[4], bfr[4];
#pragma unroll
        for (int mi = 0; mi < 4; mi++)
            af[mi] = *reinterpret_cast<const bf16x8*>(reinterpret_cast<const char*>(lds_a) + aoff[mi]);
#pragma unroll
        for (int ni = 0; ni < 4; ni++)
            bfr[ni] = *reinterpret_cast<const bf16x8*>(reinterpret_cast<const char*>(lds_b) + boff[ni]);
#pragma unroll
        for (int mi = 0; mi < 4; mi++)
#pragma unroll
            for (int ni = 0; ni < 4; ni++)
                acc[mi][ni] = __builtin_amdgcn_mfma_f32_16x16x32_bf16(af[mi], bfr[ni], acc[mi][ni], 0, 0, 0);
        __syncthreads();
    }

    float bval[4];
#pragma unroll
    for (int ni = 0; ni < 4; ni++) bval[ni] = bo[nblk + wave_n + ni * 16 + c];
#pragma unroll
    for (int mi = 0; mi < 4; mi++)
#pragma unroll
        for (int ni = 0; ni < 4; ni++) {
            int n = nblk + wave_n + ni * 16 + c;
#pragma unroll
            for (int r = 0; r < 4; r++) {
                int m = mblk + wave_m + mi * 16 + g * 4 + r;
                out[(size_t)m * D_MODEL + n] = acc[mi][ni][r] + bval[ni];
            }
        }
}

extern "C" void kernel_launch(void* const* d_in, const int* in_sizes, int n_in,
                              void* d_out, int out_size, void* d_ws, size_t ws_size,
                              hipStream_t stream) {
    const float* x    = (const float*)d_in[0];
    const int*   mask = (const int*)d_in[1];
    const float* Wq = (const float*)d_in[2];
    const float* bq = (const float*)d_in[3];
    const float* Wk = (const float*)d_in[4];
    const float* bk = (const float*)d_in[5];
    const float* Wv = (const float*)d_in[6];
    const float* bv = (const float*)d_in[7];
    const float* Wo = (const float*)d_in[8];
    const float* bo = (const float*)d_in[9];
    float* out = (float*)d_out;

    char* ws = (char*)d_ws;
    const size_t MB = 1024 * 1024;
    unsigned short* wt  = (unsigned short*)(ws + 0 * MB);
    unsigned short* xb  = (unsigned short*)(ws + 8 * MB);
    unsigned short* qb  = (unsigned short*)(ws + 24 * MB);
    unsigned short* kb  = (unsigned short*)(ws + 40 * MB);
    unsigned short* vt  = (unsigned short*)(ws + 56 * MB);
    unsigned short* ctx = (unsigned short*)(ws + 72 * MB);
    unsigned long long* mb = (unsigned long long*)(ws + 88 * MB);

    wprep<<<dim3(16, 16, 4), 256, 0, stream>>>(Wq, Wk, Wv, Wo, wt);
    xprep<<<dim3(MROWS * D_MODEL / 4 / 256), 256, 0, stream>>>((const float4*)x, xb);
    mprep<<<dim3(MROWS), 256, 0, stream>>>(mask, mb);
    qkv_gemm<<<dim3(1536), 256, 0, stream>>>(xb, wt, bq, bk, bv, qb, kb, vt);
    attn<<<dim3(1024), 128, 0, stream>>>(qb, kb, vt, mb, ctx);
    oproj<<<dim3(512), 256, 0, stream>>>(ctx, wt, bo, out);
}

// Round 14
// 348.473 us; speedup vs baseline: 1.2132x; 1.1653x over previous
//
#include <hip/hip_runtime.h>

#define D_MODEL 1024
#define N_HEADS 16
#define D_K     64
#define BATCH   4
#define SEQ     2048
#define MROWS   (BATCH * SEQ)          // 8192
// Q pre-scale: (1/sqrt(64)) * log2(e) so attn uses raw exp2
#define QSCALE  0.18033688011112042f

typedef __bf16 bf16x8 __attribute__((ext_vector_type(8)));
typedef float  f32x4  __attribute__((ext_vector_type(4)));
typedef float  f32x16 __attribute__((ext_vector_type(16)));
typedef unsigned short ushort8 __attribute__((ext_vector_type(8)));
typedef unsigned short ushort4v __attribute__((ext_vector_type(4)));

#if __has_builtin(__builtin_amdgcn_exp2f)
#define EXP2F(x) __builtin_amdgcn_exp2f(x)
#else
#define EXP2F(x) exp2f(x)
#endif

// v_cvt_pk_bf16_f32: d.lo = bf16(a), d.hi = bf16(b)  (RNE)
#define CVT_PK_BF16(d, a, b) \
    asm("v_cvt_pk_bf16_f32 %0, %1, %2" : "=v"(d) : "v"(a), "v"(b))
// v_permlane32_swap_b32 a, b: a[32:63] <-> b[0:31]
#define PERMSWAP(a, b) \
    asm("v_permlane32_swap_b32 %0, %1" : "+v"(a), "+v"(b))
// counted vmem wait: leave N newest loads in flight (T4)
#define WAIT_VM(N) asm volatile("s_waitcnt vmcnt(" #N ")" ::: "memory")
// compiler-only memory fence (pins issue order / blocks hoisting)
#define CFENCE()   asm volatile("" ::: "memory")

__device__ inline unsigned short f2bf(float f) {
    union { float f; unsigned int u; } v; v.f = f;
    unsigned int u = v.u;
    unsigned int r = (u + 0x7fffu + ((u >> 16) & 1u)) >> 16;
    return (unsigned short)r;
}

__device__ inline void load_lds16(const void* g, void* l) {
    __builtin_amdgcn_global_load_lds(
        (const __attribute__((address_space(1))) unsigned int*)g,
        (__attribute__((address_space(3))) unsigned int*)l, 16, 0, 0);
}

// ---------------- prep: weights fp32 [K][N] -> bf16 [N][K] ----------------
__global__ __launch_bounds__(256) void wprep(const float* __restrict__ Wq,
                                             const float* __restrict__ Wk,
                                             const float* __restrict__ Wv,
                                             const float* __restrict__ Wo,
                                             unsigned short* __restrict__ wt) {
    __shared__ __align__(16) unsigned short t[64][65];
    int w  = blockIdx.z;
    const float* W = (w == 0) ? Wq : (w == 1) ? Wk : (w == 2) ? Wv : Wo;
    int k0 = blockIdx.x * 64, n0 = blockIdx.y * 64;
    int tid = threadIdx.x;
    int nl = tid & 63, kq = tid >> 6;
#pragma unroll
    for (int i = 0; i < 16; i++) {
        int kl = kq * 16 + i;
        t[kl][nl] = f2bf(W[(size_t)(k0 + kl) * D_MODEL + n0 + nl]);
    }
    __syncthreads();
    unsigned short* out = wt + (size_t)w * D_MODEL * D_MODEL;
#pragma unroll
    for (int p = 0; p < 2; p++) {
        int nrow = p * 32 + (tid >> 3);
        int c8   = (tid & 7) * 8;
        ushort8 o;
#pragma unroll
        for (int j = 0; j < 8; j++) o[j] = t[c8 + j][nrow];
        *reinterpret_cast<ushort8*>(out + (size_t)(n0 + nrow) * D_MODEL + k0 + c8) = o;
    }
}

// ---------------- prep: x fp32 -> bf16 ----------------
__global__ __launch_bounds__(256) void xprep(const float4* __restrict__ x,
                                             unsigned short* __restrict__ xb) {
    int i = blockIdx.x * 256 + threadIdx.x;
    float4 v = x[i];
    ushort4v o;
    o[0] = f2bf(v.x); o[1] = f2bf(v.y); o[2] = f2bf(v.z); o[3] = f2bf(v.w);
    *reinterpret_cast<ushort4v*>(xb + (size_t)i * 4) = o;
}

// ---------------- prep: mask int32 -> bitmask (bit=1 means masked) --------
__global__ __launch_bounds__(256) void mprep(const int* __restrict__ mask,
                                             unsigned long long* __restrict__ mb) {
    int row = blockIdx.x;
    int tid = threadIdx.x;
    int wv  = tid >> 6;
#pragma unroll
    for (int w = 0; w < 8; w++) {
        int col = w * 256 + tid;
        int mval = mask[(size_t)row * SEQ + col];
        unsigned long long bits = __ballot(mval != 0);
        if ((tid & 63) == 0) mb[(size_t)row * 32 + w * 4 + wv] = bits;
    }
}

// ============ fused QKV GEMM: BK=64, M=8192 N=3072 K=1024 =================
// r6 structure (T1 swizzle, single-buffer, 2-barrier loop) with BK doubled
// 32->64: halves barrier-drain count (32->16), doubles MFMA/barrier (16->32).
// LDS 32KB (occupancy still VGPR-capped at 4 blocks/CU; m132's BK=128 loss
// was the 64KB LDS cliff, avoided here). Same linear-dest glds + XOR-swz
// source idiom, rows now 8 octets with ^(row&7).
__global__ __launch_bounds__(256) void qkv_gemm(const unsigned short* __restrict__ xb,
                                                const unsigned short* __restrict__ wt,
                                                const float* __restrict__ bq,
                                                const float* __restrict__ bk,
                                                const float* __restrict__ bvv,
                                                unsigned short* __restrict__ qb,
                                                unsigned short* __restrict__ kb,
                                                unsigned short* __restrict__ vt) {
    __shared__ __align__(16) unsigned short lds_a[128 * 64];   // 16KB
    __shared__ __align__(16) unsigned short lds_b[128 * 64];   // 16KB
    int tid = threadIdx.x;
    int wave = tid >> 6, lane = tid & 63;
    int c = lane & 15, g = lane >> 4;
    int wave_m = (wave & 1) * 64, wave_n = (wave >> 1) * 64;
    int wg = blockIdx.x;
    int swz = (wg & 7) * 192 + (wg >> 3);      // bijective: 1536 % 8 == 0
    int nblk = (swz % 24) * 128, mblk = (swz / 24) * 128;

    // staging: 1024 octets/tensor, 256/wave -> 4 glds per tensor per wave.
    // LDS pos p of row ra holds logical k-octet p^(ra&7) (XOR involution).
    const unsigned short* paA[4];
    const unsigned short* pbB[4];
    unsigned short* laA[4];
    unsigned short* lbB[4];
#pragma unroll
    for (int j = 0; j < 4; j++) {
        int oct = wave * 256 + j * 64 + lane;
        int ra  = oct >> 3;
        int ga  = ((oct & 7) ^ (ra & 7)) * 8;
        paA[j] = xb + (size_t)(mblk + ra) * D_MODEL + ga;
        pbB[j] = wt + (size_t)(nblk + ra) * D_MODEL + ga;
        laA[j] = lds_a + wave * 2048 + j * 512;
        lbB[j] = lds_b + wave * 2048 + j * 512;
    }

    // fragment byte offsets: half-K h (k = 32h..32h+31), row-major 128B rows
    int aoff[2][4], boff[2][4];
#pragma unroll
    for (int h = 0; h < 2; h++) {
#pragma unroll
        for (int mi = 0; mi < 4; mi++) {
            int row = wave_m + mi * 16 + c;
            aoff[h][mi] = (row * 8 + ((4 * h + g) ^ (row & 7))) * 16;
        }
#pragma unroll
        for (int ni = 0; ni < 4; ni++) {
            int row = wave_n + ni * 16 + c;
            boff[h][ni] = (row * 8 + ((4 * h + g) ^ (row & 7))) * 16;
        }
    }

    f32x4 acc[4][4];
#pragma unroll
    for (int mi = 0; mi < 4; mi++)
#pragma unroll
        for (int ni = 0; ni < 4; ni++) acc[mi][ni] = f32x4{0.f, 0.f, 0.f, 0.f};

    for (int k0 = 0; k0 < D_MODEL; k0 += 64) {
#pragma unroll
        for (int j = 0; j < 4; j++) {
            load_lds16(paA[j] + k0, laA[j]);
            load_lds16(pbB[j] + k0, lbB[j]);
        }
        __syncthreads();
#pragma unroll
        for (int h = 0; h < 2; h++) {
            bf16x8 af[4], bfr[4];
#pragma unroll
            for (int mi = 0; mi < 4; mi++)
                af[mi] = *reinterpret_cast<const bf16x8*>(reinterpret_cast<const char*>(lds_a) + aoff[h][mi]);
#pragma unroll
            for (int ni = 0; ni < 4; ni++)
                bfr[ni] = *reinterpret_cast<const bf16x8*>(reinterpret_cast<const char*>(lds_b) + boff[h][ni]);
#pragma unroll
            for (int mi = 0; mi < 4; mi++)
#pragma unroll
                for (int ni = 0; ni < 4; ni++)
                    acc[mi][ni] = __builtin_amdgcn_mfma_f32_16x16x32_bf16(af[mi], bfr[ni], acc[mi][ni], 0, 0, 0);
        }
        __syncthreads();
    }

    int nb = nblk + wave_n;
    int wsel = nb >> 10;
    int h = (nb >> 6) & 15;
    int dk0 = nb & 63;
    int mglob = mblk + wave_m;
    int b = mglob >> 11;
    int s0 = mglob & (SEQ - 1);
    size_t bh = (size_t)(b * N_HEADS + h);
    const float* bias = (wsel == 0) ? bq : (wsel == 1) ? bk : bvv;
    int nn = nb & (D_MODEL - 1);
    float bval[4];
#pragma unroll
    for (int ni = 0; ni < 4; ni++) bval[ni] = bias[nn + ni * 16 + c];
    float oscale = (wsel == 0) ? QSCALE : 1.0f;

    if (wsel < 2) {
        unsigned short* outp = wsel ? kb : qb;
#pragma unroll
        for (int mi = 0; mi < 4; mi++)
#pragma unroll
            for (int ni = 0; ni < 4; ni++) {
                int dk = dk0 + ni * 16 + c;
#pragma unroll
                for (int r = 0; r < 4; r++) {
                    int s = s0 + mi * 16 + g * 4 + r;
                    outp[(bh * SEQ + s) * 64 + dk] = f2bf((acc[mi][ni][r] + bval[ni]) * oscale);
                }
            }
    } else {
#pragma unroll
        for (int mi = 0; mi < 4; mi++)
#pragma unroll
            for (int ni = 0; ni < 4; ni++) {
                int dk = dk0 + ni * 16 + c;
                int s = s0 + mi * 16 + g * 4;
                ushort4v o;
#pragma unroll
                for (int r = 0; r < 4; r++) o[r] = f2bf(acc[mi][ni][r] + bval[ni]);
                *reinterpret_cast<ushort4v*>(vt + (bh * 64 + dk) * SEQ + s) = o;
            }
    }
}

// ==== flash attention v11 (proven 112us): 2 waves x 64q, dbuf, T1 swizzle ==
// Final form. v12 (4x32q), v14 (1-wave barrier-free), v15/16 (LDS-free
// direct-L2) all regressed: LDS staging is the right structure because MFMA
// fragment reads are inherently lane-scattered (32 lines/instr from L2 vs
// fast strided LDS-port reads after one coalesced glds).
__global__ __launch_bounds__(128, 2) void attn(const unsigned short* __restrict__ qb,
                                               const unsigned short* __restrict__ kb,
                                               const unsigned short* __restrict__ vt,
                                               const unsigned long long* __restrict__ mb,
                                               unsigned short* __restrict__ ctx) {
    __shared__ __align__(16) unsigned char smem[32768];
    // buffer b (b=0,1): K at smem+b*16384 ([64 key][64 dk], octet^row&7)
    //                   V at smem+b*16384+8192 ([64 dk][64 key], octet^row&7)

    int tid = threadIdx.x;
    int wave = tid >> 6, lane = tid & 63;
    int q31 = lane & 31, hi = lane >> 5;
    int bid = blockIdx.x;
    int swz = (bid & 7) * 128 + (bid >> 3);    // bijective: 1024 % 8 == 0
    int bh = swz >> 4;
    int q0 = (swz & 15) * 128 + wave * 64;
    int b = bh >> 4, h = bh & 15;
    const unsigned short* qbase = qb + (size_t)bh * SEQ * 64;
    const unsigned short* kbase = kb + (size_t)bh * SEQ * 64;
    const unsigned short* vbase = vt + (size_t)bh * 64 * SEQ;
    const unsigned long long* mp0 = mb + ((size_t)b * SEQ + q0 + q31) * 32;
    const unsigned long long* mp1 = mp0 + 1024;   // +32 rows * 32 words

    // Q B-frags for both tiles: chunk c covers dk = 16c + 8hi + (0..7)
    bf16x8 qf[2][4];
#pragma unroll
    for (int t = 0; t < 2; t++) {
        const unsigned short* qr = qbase + (size_t)(q0 + 32 * t + q31) * 64 + hi * 8;
#pragma unroll
        for (int c = 0; c < 4; c++)
            qf[t][c] = *reinterpret_cast<const bf16x8*>(qr + c * 16);
    }

    // staging: 8 rows x 128B per glds; octet xor (row&7)
    int srow = lane >> 3;
    int soct = (lane & 7) ^ srow;
    const unsigned short* ksrc[2];
    const unsigned short* vsrc[2];
    int stg[2];                 // byte offset of K-dest within buffer; V = +8192
#pragma unroll
    for (int i = 0; i < 2; i++) {
        int rbase = 16 * i + 8 * wave;
        ksrc[i] = kbase + (size_t)(rbase + srow) * 64 + soct * 8;
        vsrc[i] = vbase + (size_t)(rbase + srow) * SEQ + soct * 8;
        stg[i]  = rbase * 128;
    }
    const unsigned short* ksrc2[2];
    const unsigned short* vsrc2[2];
    int stg2[2];
#pragma unroll
    for (int i = 0; i < 2; i++) {
        int rbase = 32 + 16 * i + 8 * wave;
        ksrc2[i] = kbase + (size_t)(rbase + srow) * 64 + soct * 8;
        vsrc2[i] = vbase + (size_t)(rbase + srow) * SEQ + soct * 8;
        stg2[i]  = rbase * 128;
    }

    // K/V fragment byte offsets: subtile s (rows 32s..), chunk c
    int kofs[2][4];
#pragma unroll
    for (int s = 0; s < 2; s++)
#pragma unroll
        for (int c = 0; c < 4; c++)
            kofs[s][c] = (32 * s + q31) * 128 + (((hi + 2 * c) ^ (q31 & 7)) * 16);

    float lsum[2] = {0.f, 0.f};
    f32x16 po[2][2];
#pragma unroll
    for (int i = 0; i < 16; i++) {
        po[0][0][i] = 0.f; po[0][1][i] = 0.f;
        po[1][0][i] = 0.f; po[1][1][i] = 0.f;
    }

    // ---- prologue: masks for it=0 (issued first), then buf0 K/V loads ----
    unsigned long long mnx0 = mp0[0], mnx1 = mp1[0];
    CFENCE();
#pragma unroll
    for (int i = 0; i < 2; i++) {
        load_lds16(ksrc[i], smem + stg[i]);
        load_lds16(vsrc[i], smem + 8192 + stg[i]);
        load_lds16(ksrc2[i], smem + stg2[i]);
        load_lds16(vsrc2[i], smem + 8192 + stg2[i]);
    }

    for (int it = 0; it < SEQ / 64; it++) {
        unsigned long long w64[2];
        w64[0] = mnx0; w64[1] = mnx1;                  // current-iter masks
        int itn = (it + 1 < SEQ / 64) ? it + 1 : it;   // clamp (redundant last)
        // issue next-iter loads: masks first (so their wait is counted), glds after
        mnx0 = mp0[itn]; mnx1 = mp1[itn];
        CFENCE();
        unsigned char* bufn = smem + ((it + 1) & 1) * 16384;
#pragma unroll
        for (int i = 0; i < 2; i++) {
            load_lds16(ksrc[i] + itn * 4096, bufn + stg[i]);
            load_lds16(vsrc[i] + itn * 64,  bufn + 8192 + stg[i]);
            load_lds16(ksrc2[i] + itn * 4096, bufn + stg2[i]);
            load_lds16(vsrc2[i] + itn * 64,  bufn + 8192 + stg2[i]);
        }
        WAIT_VM(10);                      // drain all but this iter's 10 ops
        __builtin_amdgcn_s_barrier();     // buf[cur] complete across all waves
        CFENCE();

        const char* lkb = (const char*)(smem + (it & 1) * 16384);
        const char* lvb = lkb + 8192;

#pragma unroll
        for (int s = 0; s < 2; s++) {
            // QK^T (S^T): A=K rows(keys 32s..32s+31), B=Q[t] -> col=query
            f32x16 sq[2];
#pragma unroll
            for (int i = 0; i < 16; i++) { sq[0][i] = 0.f; sq[1][i] = 0.f; }
#pragma unroll
            for (int c = 0; c < 4; c++) {
                bf16x8 kf = *reinterpret_cast<const bf16x8*>(lkb + kofs[s][c]);
                sq[0] = __builtin_amdgcn_mfma_f32_32x32x16_bf16(kf, qf[0][c], sq[0], 0, 0, 0);
                sq[1] = __builtin_amdgcn_mfma_f32_32x32x16_bf16(kf, qf[1][c], sq[1], 0, 0, 0);
            }
            // softmax numerators + in-register P^T fragment build.
            // reg r of sq holds key (r&3) + 8*(r>>2) + 4*hi (within subtile).
            union PF { uint4 u; bf16x8 v; };
            PF pf[2][2];   // [t][cp]
#pragma unroll
            for (int t = 0; t < 2; t++) {
                unsigned int wt_ = ~(unsigned int)(w64[t] >> (32 * s));   // bit=1 -> keep
                float pm[16];
#pragma unroll
                for (int j = 0; j < 4; j++) {
                    unsigned int nj = wt_ >> (8 * j + 4 * hi);
#pragma unroll
                    for (int e = 0; e < 4; e++) {
                        float p = EXP2F(sq[t][4 * j + e]);
                        unsigned int m = (unsigned int)((int)(nj << (31 - e)) >> 31);
                        unsigned int pu = __float_as_uint(p) & m;
                        pm[4 * j + e] = __uint_as_float(pu);
                        lsum[t] += __uint_as_float(pu);
                    }
                }
                // pack pairs of consecutive keys: word w[2j+u] = keys 8j+4hi+2u+{0,1}
                unsigned int w[8];
#pragma unroll
                for (int j = 0; j < 4; j++) {
                    CVT_PK_BF16(w[2 * j],     pm[4 * j + 0], pm[4 * j + 1]);
                    CVT_PK_BF16(w[2 * j + 1], pm[4 * j + 2], pm[4 * j + 3]);
                }
                // redistribute hi/lo lane halves into B-fragment word order:
                // after swap(w0,w2): w0 = frag word0 (keys 2m..), w2 = word2
                PERMSWAP(w[0], w[2]); PERMSWAP(w[1], w[3]);   // cp=0 (keys 0..15)
                PERMSWAP(w[4], w[6]); PERMSWAP(w[5], w[7]);   // cp=1 (keys 16..31)
                pf[t][0].u = uint4{w[0], w[1], w[2], w[3]};
                pf[t][1].u = uint4{w[4], w[5], w[6], w[7]};
            }
            // PV (O^T): A=V^T rows(dk), B=P^T -> col=query
#pragma unroll
            for (int cp = 0; cp < 2; cp++) {
                int c = 2 * s + cp;
#pragma unroll
                for (int so = 0; so < 2; so++) {
                    bf16x8 vf = *reinterpret_cast<const bf16x8*>(lvb + kofs[so][c]);
                    po[0][so] = __builtin_amdgcn_mfma_f32_32x32x16_bf16(vf, pf[0][cp].v, po[0][so], 0, 0, 0);
                    po[1][so] = __builtin_amdgcn_mfma_f32_32x32x16_bf16(vf, pf[1][cp].v, po[1][so], 0, 0, 0);
                }
            }
        }
        CFENCE();
        __builtin_amdgcn_s_barrier();     // all waves done reading buf[cur]
    }

    // drain the redundant last-iter glds (they target buf0, reused below)
    WAIT_VM(0);
    __builtin_amdgcn_s_barrier();

    // finish row sums: partner (lane^32) holds the complementary key halves
    float inv[2];
#pragma unroll
    for (int t = 0; t < 2; t++) {
        lsum[t] += __shfl_xor(lsum[t], 32);
        inv[t] = 1.f / lsum[t];
    }

    // epilogue: normalize O^T (dk = 32so + 8j + 4hi + e), bounce via LDS
    unsigned int* ob = (unsigned int*)(smem + wave * 8192);
    int csw = 4 * (q31 & 7);
#pragma unroll
    for (int t = 0; t < 2; t++) {
        unsigned int* obr = ob + (32 * t + q31) * 32;
#pragma unroll
        for (int so = 0; so < 2; so++)
#pragma unroll
            for (int j = 0; j < 4; j++) {
                unsigned int w0 = (unsigned int)f2bf(po[t][so][4 * j + 0] * inv[t])
                                | ((unsigned int)f2bf(po[t][so][4 * j + 1] * inv[t]) << 16);
                unsigned int w1 = (unsigned int)f2bf(po[t][so][4 * j + 2] * inv[t])
                                | ((unsigned int)f2bf(po[t][so][4 * j + 3] * inv[t]) << 16);
                int d = (16 * so + 4 * j + 2 * hi) ^ csw;
                uint2 u; u.x = w0; u.y = w1;
                *reinterpret_cast<uint2*>(obr + d) = u;
            }
    }
    __builtin_amdgcn_s_waitcnt(0);   // drain own ds_writes (wave-private region)
    size_t crow = (size_t)b * SEQ + q0;
    int o = lane & 7, rl = lane >> 3;
#pragma unroll
    for (int i = 0; i < 8; i++) {
        int r = 8 * i + rl;
        uint4 v = *reinterpret_cast<const uint4*>(ob + r * 32 + 4 * (o ^ (r & 7)));
        *reinterpret_cast<uint4*>(ctx + (crow + r) * D_MODEL + h * 64 + o * 8) = v;
    }
}

// ============ output projection: m97 structure, M=8192 N=1024 K=1024 ======
// Round-6 form (proven): T1 swizzle, single-buffer 2-barrier loop.
__global__ __launch_bounds__(256) void oproj(const unsigned short* __restrict__ ctx,
                                             const unsigned short* __restrict__ wt,
                                             const float* __restrict__ bo,
                                             float* __restrict__ out) {
    __shared__ __align__(16) unsigned short lds_a[128 * 32];
    __shared__ __align__(16) unsigned short lds_b[128 * 32];
    int tid = threadIdx.x;
    int wave = tid >> 6, lane = tid & 63;
    int c = lane & 15, g = lane >> 4;
    int wave_m = (wave & 1) * 64, wave_n = (wave >> 1) * 64;
    int wg = blockIdx.x;
    int swz = (wg & 7) * 64 + (wg >> 3);       // bijective: 512 % 8 == 0
    int nblk = (swz & 7) * 128, mblk = (swz >> 3) * 128;
    const unsigned short* wo = wt + (size_t)3 * D_MODEL * D_MODEL;

    int oct0 = wave * 128 + lane, oct1 = oct0 + 64;
    int ra0 = oct0 >> 2, ga0 = ((oct0 & 3) ^ (ra0 & 3)) * 8;
    int ra1 = oct1 >> 2, ga1 = ((oct1 & 3) ^ (ra1 & 3)) * 8;
    const unsigned short* pa0 = ctx + (size_t)(mblk + ra0) * D_MODEL + ga0;
    const unsigned short* pa1 = ctx + (size_t)(mblk + ra1) * D_MODEL + ga1;
    const unsigned short* pb0 = wo + (size_t)(nblk + ra0) * D_MODEL + ga0;
    const unsigned short* pb1 = wo + (size_t)(nblk + ra1) * D_MODEL + ga1;
    unsigned short* la0 = lds_a + wave * 1024;
    unsigned short* la1 = la0 + 512;
    unsigned short* lb0 = lds_b + wave * 1024;
    unsigned short* lb1 = lb0 + 512;

    int aoff[4], boff[4];
#pragma unroll
    for (int mi = 0; mi < 4; mi++) {
        int row = wave_m + mi * 16 + c;
        aoff[mi] = (row * 4 + (g ^ (row & 3))) * 16;
    }
#pragma unroll
    for (int ni = 0; ni < 4; ni++) {
        int row = wave_n + ni * 16 + c;
        boff[ni] = (row * 4 + (g ^ (row & 3))) * 16;
    }

    f32x4 acc[4][4];
#pragma unroll
    for (int mi = 0; mi < 4; mi++)
#pragma unroll
        for (int ni = 0; ni < 4; ni++) acc[mi][ni] = f32x4{0.f, 0.f, 0.f, 0.f};

    for (int k0 = 0; k0 < D_MODEL; k0 += 32) {
        load_lds16(pa0 + k0, la0);
        load_lds16(pa1 + k0, la1);
        load_lds16(pb0 + k0, lb0);
        load_lds16(pb1 + k0, lb1);
        __syncthreads();
        bf16x8 af[4], bfr[4];
#pragma unroll
        for (int mi = 0; mi < 4; mi++)
            af[mi] = *reinterpret_cast<const bf16x8*>(reinterpret_cast<const char*>(lds_a) + aoff[mi]);
#pragma unroll
        for (int ni = 0; ni < 4; ni++)
            bfr[ni] = *reinterpret_cast<const bf16x8*>(reinterpret_cast<const char*>(lds_b) + boff[ni]);
#pragma unroll
        for (int mi = 0; mi < 4; mi++)
#pragma unroll
            for (int ni = 0; ni < 4; ni++)
                acc[mi][ni] = __builtin_amdgcn_mfma_f32_16x16x32_bf16(af[mi], bfr[ni], acc[mi][ni], 0, 0, 0);
        __syncthreads();
    }

    float bval[4];
#pragma unroll
    for (int ni = 0; ni < 4; ni++) bval[ni] = bo[nblk + wave_n + ni * 16 + c];
#pragma unroll
    for (int mi = 0; mi < 4; mi++)
#pragma unroll
        for (int ni = 0; ni < 4; ni++) {
            int n = nblk + wave_n + ni * 16 + c;
#pragma unroll
            for (int r = 0; r < 4; r++) {
                int m = mblk + wave_m + mi * 16 + g * 4 + r;
                out[(size_t)m * D_MODEL + n] = acc[mi][ni][r] + bval[ni];
            }
        }
}

extern "C" void kernel_launch(void* const* d_in, const int* in_sizes, int n_in,
                              void* d_out, int out_size, void* d_ws, size_t ws_size,
                              hipStream_t stream) {
    const float* x    = (const float*)d_in[0];
    const int*   mask = (const int*)d_in[1];
    const float* Wq = (const float*)d_in[2];
    const float* bq = (const float*)d_in[3];
    const float* Wk = (const float*)d_in[4];
    const float* bk = (const float*)d_in[5];
    const float* Wv = (const float*)d_in[6];
    const float* bv = (const float*)d_in[7];
    const float* Wo = (const float*)d_in[8];
    const float* bo = (const float*)d_in[9];
    float* out = (float*)d_out;

    char* ws = (char*)d_ws;
    const size_t MB = 1024 * 1024;
    unsigned short* wt  = (unsigned short*)(ws + 0 * MB);
    unsigned short* xb  = (unsigned short*)(ws + 8 * MB);
    unsigned short* qb  = (unsigned short*)(ws + 24 * MB);
    unsigned short* kb  = (unsigned short*)(ws + 40 * MB);
    unsigned short* vt  = (unsigned short*)(ws + 56 * MB);
    unsigned short* ctx = (unsigned short*)(ws + 72 * MB);
    unsigned long long* mb = (unsigned long long*)(ws + 88 * MB);

    wprep<<<dim3(16, 16, 4), 256, 0, stream>>>(Wq, Wk, Wv, Wo, wt);
    xprep<<<dim3(MROWS * D_MODEL / 4 / 256), 256, 0, stream>>>((const float4*)x, xb);
    mprep<<<dim3(MROWS), 256, 0, stream>>>(mask, mb);
    qkv_gemm<<<dim3(1536), 256, 0, stream>>>(xb, wt, bq, bk, bv, qb, kb, vt);
    attn<<<dim3(1024), 128, 0, stream>>>(qb, kb, vt, mb, ctx);
    oproj<<<dim3(512), 256, 0, stream>>>(ctx, wt, bo, out);
}

// Round 15
// 342.436 us; speedup vs baseline: 1.2346x; 1.0176x over previous
//
#include <hip/hip_runtime.h>

#define D_MODEL 1024
#define N_HEADS 16
#define D_K     64
#define BATCH   4
#define SEQ     2048
#define MROWS   (BATCH * SEQ)          // 8192
// Q pre-scale: (1/sqrt(64)) * log2(e) so attn uses raw exp2
#define QSCALE  0.18033688011112042f

typedef __bf16 bf16x8 __attribute__((ext_vector_type(8)));
typedef float  f32x4  __attribute__((ext_vector_type(4)));
typedef float  f32x16 __attribute__((ext_vector_type(16)));
typedef unsigned short ushort8 __attribute__((ext_vector_type(8)));
typedef unsigned short ushort4v __attribute__((ext_vector_type(4)));

#if __has_builtin(__builtin_amdgcn_exp2f)
#define EXP2F(x) __builtin_amdgcn_exp2f(x)
#else
#define EXP2F(x) exp2f(x)
#endif

// v_cvt_pk_bf16_f32: d.lo = bf16(a), d.hi = bf16(b)  (RNE)
#define CVT_PK_BF16(d, a, b) \
    asm("v_cvt_pk_bf16_f32 %0, %1, %2" : "=v"(d) : "v"(a), "v"(b))
// v_permlane32_swap_b32 a, b: a[32:63] <-> b[0:31]
#define PERMSWAP(a, b) \
    asm("v_permlane32_swap_b32 %0, %1" : "+v"(a), "+v"(b))
// counted vmem wait: leave N newest loads in flight (T4)
#define WAIT_VM(N) asm volatile("s_waitcnt vmcnt(" #N ")" ::: "memory")
// compiler-only memory fence (pins issue order / blocks hoisting)
#define CFENCE()   asm volatile("" ::: "memory")

__device__ inline unsigned short f2bf(float f) {
    union { float f; unsigned int u; } v; v.f = f;
    unsigned int u = v.u;
    unsigned int r = (u + 0x7fffu + ((u >> 16) & 1u)) >> 16;
    return (unsigned short)r;
}

__device__ inline void load_lds16(const void* g, void* l) {
    __builtin_amdgcn_global_load_lds(
        (const __attribute__((address_space(1))) unsigned int*)g,
        (__attribute__((address_space(3))) unsigned int*)l, 16, 0, 0);
}

// ---------------- prep: weights fp32 [K][N] -> bf16 [N][K] ----------------
__global__ __launch_bounds__(256) void wprep(const float* __restrict__ Wq,
                                             const float* __restrict__ Wk,
                                             const float* __restrict__ Wv,
                                             const float* __restrict__ Wo,
                                             unsigned short* __restrict__ wt) {
    __shared__ __align__(16) unsigned short t[64][65];
    int w  = blockIdx.z;
    const float* W = (w == 0) ? Wq : (w == 1) ? Wk : (w == 2) ? Wv : Wo;
    int k0 = blockIdx.x * 64, n0 = blockIdx.y * 64;
    int tid = threadIdx.x;
    int nl = tid & 63, kq = tid >> 6;
#pragma unroll
    for (int i = 0; i < 16; i++) {
        int kl = kq * 16 + i;
        t[kl][nl] = f2bf(W[(size_t)(k0 + kl) * D_MODEL + n0 + nl]);
    }
    __syncthreads();
    unsigned short* out = wt + (size_t)w * D_MODEL * D_MODEL;
#pragma unroll
    for (int p = 0; p < 2; p++) {
        int nrow = p * 32 + (tid >> 3);
        int c8   = (tid & 7) * 8;
        ushort8 o;
#pragma unroll
        for (int j = 0; j < 8; j++) o[j] = t[c8 + j][nrow];
        *reinterpret_cast<ushort8*>(out + (size_t)(n0 + nrow) * D_MODEL + k0 + c8) = o;
    }
}

// ---------------- prep: x fp32 -> bf16 ----------------
__global__ __launch_bounds__(256) void xprep(const float4* __restrict__ x,
                                             unsigned short* __restrict__ xb) {
    int i = blockIdx.x * 256 + threadIdx.x;
    float4 v = x[i];
    ushort4v o;
    o[0] = f2bf(v.x); o[1] = f2bf(v.y); o[2] = f2bf(v.z); o[3] = f2bf(v.w);
    *reinterpret_cast<ushort4v*>(xb + (size_t)i * 4) = o;
}

// ---------------- prep: mask int32 -> bitmask (bit=1 means masked) --------
__global__ __launch_bounds__(256) void mprep(const int* __restrict__ mask,
                                             unsigned long long* __restrict__ mb) {
    int row = blockIdx.x;
    int tid = threadIdx.x;
    int wv  = tid >> 6;
#pragma unroll
    for (int w = 0; w < 8; w++) {
        int col = w * 256 + tid;
        int mval = mask[(size_t)row * SEQ + col];
        unsigned long long bits = __ballot(mval != 0);
        if ((tid & 63) == 0) mb[(size_t)row * 32 + w * 4 + wv] = bits;
    }
}

// ============ fused QKV GEMM: BK=64, M=8192 N=3072 K=1024 =================
// r14-proven: T1 swizzle + BK=64 (halved barrier drains, 32 MFMA/barrier).
__global__ __launch_bounds__(256) void qkv_gemm(const unsigned short* __restrict__ xb,
                                                const unsigned short* __restrict__ wt,
                                                const float* __restrict__ bq,
                                                const float* __restrict__ bk,
                                                const float* __restrict__ bvv,
                                                unsigned short* __restrict__ qb,
                                                unsigned short* __restrict__ kb,
                                                unsigned short* __restrict__ vt) {
    __shared__ __align__(16) unsigned short lds_a[128 * 64];   // 16KB
    __shared__ __align__(16) unsigned short lds_b[128 * 64];   // 16KB
    int tid = threadIdx.x;
    int wave = tid >> 6, lane = tid & 63;
    int c = lane & 15, g = lane >> 4;
    int wave_m = (wave & 1) * 64, wave_n = (wave >> 1) * 64;
    int wg = blockIdx.x;
    int swz = (wg & 7) * 192 + (wg >> 3);      // bijective: 1536 % 8 == 0
    int nblk = (swz % 24) * 128, mblk = (swz / 24) * 128;

    // staging: 1024 octets/tensor, 256/wave -> 4 glds per tensor per wave.
    // LDS pos p of row ra holds logical k-octet p^(ra&7) (XOR involution).
    const unsigned short* paA[4];
    const unsigned short* pbB[4];
    unsigned short* laA[4];
    unsigned short* lbB[4];
#pragma unroll
    for (int j = 0; j < 4; j++) {
        int oct = wave * 256 + j * 64 + lane;
        int ra  = oct >> 3;
        int ga  = ((oct & 7) ^ (ra & 7)) * 8;
        paA[j] = xb + (size_t)(mblk + ra) * D_MODEL + ga;
        pbB[j] = wt + (size_t)(nblk + ra) * D_MODEL + ga;
        laA[j] = lds_a + wave * 2048 + j * 512;
        lbB[j] = lds_b + wave * 2048 + j * 512;
    }

    // fragment byte offsets: half-K h (k = 32h..32h+31), row-major 128B rows
    int aoff[2][4], boff[2][4];
#pragma unroll
    for (int h = 0; h < 2; h++) {
#pragma unroll
        for (int mi = 0; mi < 4; mi++) {
            int row = wave_m + mi * 16 + c;
            aoff[h][mi] = (row * 8 + ((4 * h + g) ^ (row & 7))) * 16;
        }
#pragma unroll
        for (int ni = 0; ni < 4; ni++) {
            int row = wave_n + ni * 16 + c;
            boff[h][ni] = (row * 8 + ((4 * h + g) ^ (row & 7))) * 16;
        }
    }

    f32x4 acc[4][4];
#pragma unroll
    for (int mi = 0; mi < 4; mi++)
#pragma unroll
        for (int ni = 0; ni < 4; ni++) acc[mi][ni] = f32x4{0.f, 0.f, 0.f, 0.f};

    for (int k0 = 0; k0 < D_MODEL; k0 += 64) {
#pragma unroll
        for (int j = 0; j < 4; j++) {
            load_lds16(paA[j] + k0, laA[j]);
            load_lds16(pbB[j] + k0, lbB[j]);
        }
        __syncthreads();
#pragma unroll
        for (int h = 0; h < 2; h++) {
            bf16x8 af[4], bfr[4];
#pragma unroll
            for (int mi = 0; mi < 4; mi++)
                af[mi] = *reinterpret_cast<const bf16x8*>(reinterpret_cast<const char*>(lds_a) + aoff[h][mi]);
#pragma unroll
            for (int ni = 0; ni < 4; ni++)
                bfr[ni] = *reinterpret_cast<const bf16x8*>(reinterpret_cast<const char*>(lds_b) + boff[h][ni]);
#pragma unroll
            for (int mi = 0; mi < 4; mi++)
#pragma unroll
                for (int ni = 0; ni < 4; ni++)
                    acc[mi][ni] = __builtin_amdgcn_mfma_f32_16x16x32_bf16(af[mi], bfr[ni], acc[mi][ni], 0, 0, 0);
        }
        __syncthreads();
    }

    int nb = nblk + wave_n;
    int wsel = nb >> 10;
    int h = (nb >> 6) & 15;
    int dk0 = nb & 63;
    int mglob = mblk + wave_m;
    int b = mglob >> 11;
    int s0 = mglob & (SEQ - 1);
    size_t bh = (size_t)(b * N_HEADS + h);
    const float* bias = (wsel == 0) ? bq : (wsel == 1) ? bk : bvv;
    int nn = nb & (D_MODEL - 1);
    float bval[4];
#pragma unroll
    for (int ni = 0; ni < 4; ni++) bval[ni] = bias[nn + ni * 16 + c];
    float oscale = (wsel == 0) ? QSCALE : 1.0f;

    if (wsel < 2) {
        unsigned short* outp = wsel ? kb : qb;
#pragma unroll
        for (int mi = 0; mi < 4; mi++)
#pragma unroll
            for (int ni = 0; ni < 4; ni++) {
                int dk = dk0 + ni * 16 + c;
#pragma unroll
                for (int r = 0; r < 4; r++) {
                    int s = s0 + mi * 16 + g * 4 + r;
                    outp[(bh * SEQ + s) * 64 + dk] = f2bf((acc[mi][ni][r] + bval[ni]) * oscale);
                }
            }
    } else {
#pragma unroll
        for (int mi = 0; mi < 4; mi++)
#pragma unroll
            for (int ni = 0; ni < 4; ni++) {
                int dk = dk0 + ni * 16 + c;
                int s = s0 + mi * 16 + g * 4;
                ushort4v o;
#pragma unroll
                for (int r = 0; r < 4; r++) o[r] = f2bf(acc[mi][ni][r] + bval[ni]);
                *reinterpret_cast<ushort4v*>(vt + (bh * 64 + dk) * SEQ + s) = o;
            }
    }
}

// ==== flash attention v11 (proven 111us): 2 waves x 64q, dbuf, T1 swizzle ==
// Final form. v12 (4x32q), v14 (1-wave barrier-free), v15/16 (LDS-free
// direct-L2) all regressed: LDS staging is the right structure because MFMA
// fragment reads are inherently lane-scattered (32 lines/instr from L2 vs
// fast strided LDS-port reads after one coalesced glds).
__global__ __launch_bounds__(128, 2) void attn(const unsigned short* __restrict__ qb,
                                               const unsigned short* __restrict__ kb,
                                               const unsigned short* __restrict__ vt,
                                               const unsigned long long* __restrict__ mb,
                                               unsigned short* __restrict__ ctx) {
    __shared__ __align__(16) unsigned char smem[32768];
    // buffer b (b=0,1): K at smem+b*16384 ([64 key][64 dk], octet^row&7)
    //                   V at smem+b*16384+8192 ([64 dk][64 key], octet^row&7)

    int tid = threadIdx.x;
    int wave = tid >> 6, lane = tid & 63;
    int q31 = lane & 31, hi = lane >> 5;
    int bid = blockIdx.x;
    int swz = (bid & 7) * 128 + (bid >> 3);    // bijective: 1024 % 8 == 0
    int bh = swz >> 4;
    int q0 = (swz & 15) * 128 + wave * 64;
    int b = bh >> 4, h = bh & 15;
    const unsigned short* qbase = qb + (size_t)bh * SEQ * 64;
    const unsigned short* kbase = kb + (size_t)bh * SEQ * 64;
    const unsigned short* vbase = vt + (size_t)bh * 64 * SEQ;
    const unsigned long long* mp0 = mb + ((size_t)b * SEQ + q0 + q31) * 32;
    const unsigned long long* mp1 = mp0 + 1024;   // +32 rows * 32 words

    // Q B-frags for both tiles: chunk c covers dk = 16c + 8hi + (0..7)
    bf16x8 qf[2][4];
#pragma unroll
    for (int t = 0; t < 2; t++) {
        const unsigned short* qr = qbase + (size_t)(q0 + 32 * t + q31) * 64 + hi * 8;
#pragma unroll
        for (int c = 0; c < 4; c++)
            qf[t][c] = *reinterpret_cast<const bf16x8*>(qr + c * 16);
    }

    // staging: 8 rows x 128B per glds; octet xor (row&7)
    int srow = lane >> 3;
    int soct = (lane & 7) ^ srow;
    const unsigned short* ksrc[2];
    const unsigned short* vsrc[2];
    int stg[2];                 // byte offset of K-dest within buffer; V = +8192
#pragma unroll
    for (int i = 0; i < 2; i++) {
        int rbase = 16 * i + 8 * wave;
        ksrc[i] = kbase + (size_t)(rbase + srow) * 64 + soct * 8;
        vsrc[i] = vbase + (size_t)(rbase + srow) * SEQ + soct * 8;
        stg[i]  = rbase * 128;
    }
    const unsigned short* ksrc2[2];
    const unsigned short* vsrc2[2];
    int stg2[2];
#pragma unroll
    for (int i = 0; i < 2; i++) {
        int rbase = 32 + 16 * i + 8 * wave;
        ksrc2[i] = kbase + (size_t)(rbase + srow) * 64 + soct * 8;
        vsrc2[i] = vbase + (size_t)(rbase + srow) * SEQ + soct * 8;
        stg2[i]  = rbase * 128;
    }

    // K/V fragment byte offsets: subtile s (rows 32s..), chunk c
    int kofs[2][4];
#pragma unroll
    for (int s = 0; s < 2; s++)
#pragma unroll
        for (int c = 0; c < 4; c++)
            kofs[s][c] = (32 * s + q31) * 128 + (((hi + 2 * c) ^ (q31 & 7)) * 16);

    float lsum[2] = {0.f, 0.f};
    f32x16 po[2][2];
#pragma unroll
    for (int i = 0; i < 16; i++) {
        po[0][0][i] = 0.f; po[0][1][i] = 0.f;
        po[1][0][i] = 0.f; po[1][1][i] = 0.f;
    }

    // ---- prologue: masks for it=0 (issued first), then buf0 K/V loads ----
    unsigned long long mnx0 = mp0[0], mnx1 = mp1[0];
    CFENCE();
#pragma unroll
    for (int i = 0; i < 2; i++) {
        load_lds16(ksrc[i], smem + stg[i]);
        load_lds16(vsrc[i], smem + 8192 + stg[i]);
        load_lds16(ksrc2[i], smem + stg2[i]);
        load_lds16(vsrc2[i], smem + 8192 + stg2[i]);
    }

    for (int it = 0; it < SEQ / 64; it++) {
        unsigned long long w64[2];
        w64[0] = mnx0; w64[1] = mnx1;                  // current-iter masks
        int itn = (it + 1 < SEQ / 64) ? it + 1 : it;   // clamp (redundant last)
        // issue next-iter loads: masks first (so their wait is counted), glds after
        mnx0 = mp0[itn]; mnx1 = mp1[itn];
        CFENCE();
        unsigned char* bufn = smem + ((it + 1) & 1) * 16384;
#pragma unroll
        for (int i = 0; i < 2; i++) {
            load_lds16(ksrc[i] + itn * 4096, bufn + stg[i]);
            load_lds16(vsrc[i] + itn * 64,  bufn + 8192 + stg[i]);
            load_lds16(ksrc2[i] + itn * 4096, bufn + stg2[i]);
            load_lds16(vsrc2[i] + itn * 64,  bufn + 8192 + stg2[i]);
        }
        WAIT_VM(10);                      // drain all but this iter's 10 ops
        __builtin_amdgcn_s_barrier();     // buf[cur] complete across all waves
        CFENCE();

        const char* lkb = (const char*)(smem + (it & 1) * 16384);
        const char* lvb = lkb + 8192;

#pragma unroll
        for (int s = 0; s < 2; s++) {
            // QK^T (S^T): A=K rows(keys 32s..32s+31), B=Q[t] -> col=query
            f32x16 sq[2];
#pragma unroll
            for (int i = 0; i < 16; i++) { sq[0][i] = 0.f; sq[1][i] = 0.f; }
#pragma unroll
            for (int c = 0; c < 4; c++) {
                bf16x8 kf = *reinterpret_cast<const bf16x8*>(lkb + kofs[s][c]);
                sq[0] = __builtin_amdgcn_mfma_f32_32x32x16_bf16(kf, qf[0][c], sq[0], 0, 0, 0);
                sq[1] = __builtin_amdgcn_mfma_f32_32x32x16_bf16(kf, qf[1][c], sq[1], 0, 0, 0);
            }
            // softmax numerators + in-register P^T fragment build.
            // reg r of sq holds key (r&3) + 8*(r>>2) + 4*hi (within subtile).
            union PF { uint4 u; bf16x8 v; };
            PF pf[2][2];   // [t][cp]
#pragma unroll
            for (int t = 0; t < 2; t++) {
                unsigned int wt_ = ~(unsigned int)(w64[t] >> (32 * s));   // bit=1 -> keep
                float pm[16];
#pragma unroll
                for (int j = 0; j < 4; j++) {
                    unsigned int nj = wt_ >> (8 * j + 4 * hi);
#pragma unroll
                    for (int e = 0; e < 4; e++) {
                        float p = EXP2F(sq[t][4 * j + e]);
                        unsigned int m = (unsigned int)((int)(nj << (31 - e)) >> 31);
                        unsigned int pu = __float_as_uint(p) & m;
                        pm[4 * j + e] = __uint_as_float(pu);
                        lsum[t] += __uint_as_float(pu);
                    }
                }
                // pack pairs of consecutive keys: word w[2j+u] = keys 8j+4hi+2u+{0,1}
                unsigned int w[8];
#pragma unroll
                for (int j = 0; j < 4; j++) {
                    CVT_PK_BF16(w[2 * j],     pm[4 * j + 0], pm[4 * j + 1]);
                    CVT_PK_BF16(w[2 * j + 1], pm[4 * j + 2], pm[4 * j + 3]);
                }
                // redistribute hi/lo lane halves into B-fragment word order:
                // after swap(w0,w2): w0 = frag word0 (keys 2m..), w2 = word2
                PERMSWAP(w[0], w[2]); PERMSWAP(w[1], w[3]);   // cp=0 (keys 0..15)
                PERMSWAP(w[4], w[6]); PERMSWAP(w[5], w[7]);   // cp=1 (keys 16..31)
                pf[t][0].u = uint4{w[0], w[1], w[2], w[3]};
                pf[t][1].u = uint4{w[4], w[5], w[6], w[7]};
            }
            // PV (O^T): A=V^T rows(dk), B=P^T -> col=query
#pragma unroll
            for (int cp = 0; cp < 2; cp++) {
                int c = 2 * s + cp;
#pragma unroll
                for (int so = 0; so < 2; so++) {
                    bf16x8 vf = *reinterpret_cast<const bf16x8*>(lvb + kofs[so][c]);
                    po[0][so] = __builtin_amdgcn_mfma_f32_32x32x16_bf16(vf, pf[0][cp].v, po[0][so], 0, 0, 0);
                    po[1][so] = __builtin_amdgcn_mfma_f32_32x32x16_bf16(vf, pf[1][cp].v, po[1][so], 0, 0, 0);
                }
            }
        }
        CFENCE();
        __builtin_amdgcn_s_barrier();     // all waves done reading buf[cur]
    }

    // drain the redundant last-iter glds (they target buf0, reused below)
    WAIT_VM(0);
    __builtin_amdgcn_s_barrier();

    // finish row sums: partner (lane^32) holds the complementary key halves
    float inv[2];
#pragma unroll
    for (int t = 0; t < 2; t++) {
        lsum[t] += __shfl_xor(lsum[t], 32);
        inv[t] = 1.f / lsum[t];
    }

    // epilogue: normalize O^T (dk = 32so + 8j + 4hi + e), bounce via LDS
    unsigned int* ob = (unsigned int*)(smem + wave * 8192);
    int csw = 4 * (q31 & 7);
#pragma unroll
    for (int t = 0; t < 2; t++) {
        unsigned int* obr = ob + (32 * t + q31) * 32;
#pragma unroll
        for (int so = 0; so < 2; so++)
#pragma unroll
            for (int j = 0; j < 4; j++) {
                unsigned int w0 = (unsigned int)f2bf(po[t][so][4 * j + 0] * inv[t])
                                | ((unsigned int)f2bf(po[t][so][4 * j + 1] * inv[t]) << 16);
                unsigned int w1 = (unsigned int)f2bf(po[t][so][4 * j + 2] * inv[t])
                                | ((unsigned int)f2bf(po[t][so][4 * j + 3] * inv[t]) << 16);
                int d = (16 * so + 4 * j + 2 * hi) ^ csw;
                uint2 u; u.x = w0; u.y = w1;
                *reinterpret_cast<uint2*>(obr + d) = u;
            }
    }
    __builtin_amdgcn_s_waitcnt(0);   // drain own ds_writes (wave-private region)
    size_t crow = (size_t)b * SEQ + q0;
    int o = lane & 7, rl = lane >> 3;
#pragma unroll
    for (int i = 0; i < 8; i++) {
        int r = 8 * i + rl;
        uint4 v = *reinterpret_cast<const uint4*>(ob + r * 32 + 4 * (o ^ (r & 7)));
        *reinterpret_cast<uint4*>(ctx + (crow + r) * D_MODEL + h * 64 + o * 8) = v;
    }
}

// ============ output projection: BK=64, M=8192 N=1024 K=1024 ==============
// r14-proven BK=64 transform applied (same staging/fragment code as qkv).
__global__ __launch_bounds__(256) void oproj(const unsigned short* __restrict__ ctx,
                                             const unsigned short* __restrict__ wt,
                                             const float* __restrict__ bo,
                                             float* __restrict__ out) {
    __shared__ __align__(16) unsigned short lds_a[128 * 64];   // 16KB
    __shared__ __align__(16) unsigned short lds_b[128 * 64];   // 16KB
    int tid = threadIdx.x;
    int wave = tid >> 6, lane = tid & 63;
    int c = lane & 15, g = lane >> 4;
    int wave_m = (wave & 1) * 64, wave_n = (wave >> 1) * 64;
    int wg = blockIdx.x;
    int swz = (wg & 7) * 64 + (wg >> 3);       // bijective: 512 % 8 == 0
    int nblk = (swz & 7) * 128, mblk = (swz >> 3) * 128;
    const unsigned short* wo = wt + (size_t)3 * D_MODEL * D_MODEL;

    const unsigned short* paA[4];
    const unsigned short* pbB[4];
    unsigned short* laA[4];
    unsigned short* lbB[4];
#pragma unroll
    for (int j = 0; j < 4; j++) {
        int oct = wave * 256 + j * 64 + lane;
        int ra  = oct >> 3;
        int ga  = ((oct & 7) ^ (ra & 7)) * 8;
        paA[j] = ctx + (size_t)(mblk + ra) * D_MODEL + ga;
        pbB[j] = wo + (size_t)(nblk + ra) * D_MODEL + ga;
        laA[j] = lds_a + wave * 2048 + j * 512;
        lbB[j] = lds_b + wave * 2048 + j * 512;
    }

    int aoff[2][4], boff[2][4];
#pragma unroll
    for (int h = 0; h < 2; h++) {
#pragma unroll
        for (int mi = 0; mi < 4; mi++) {
            int row = wave_m + mi * 16 + c;
            aoff[h][mi] = (row * 8 + ((4 * h + g) ^ (row & 7))) * 16;
        }
#pragma unroll
        for (int ni = 0; ni < 4; ni++) {
            int row = wave_n + ni * 16 + c;
            boff[h][ni] = (row * 8 + ((4 * h + g) ^ (row & 7))) * 16;
        }
    }

    f32x4 acc[4][4];
#pragma unroll
    for (int mi = 0; mi < 4; mi++)
#pragma unroll
        for (int ni = 0; ni < 4; ni++) acc[mi][ni] = f32x4{0.f, 0.f, 0.f, 0.f};

    for (int k0 = 0; k0 < D_MODEL; k0 += 64) {
#pragma unroll
        for (int j = 0; j < 4; j++) {
            load_lds16(paA[j] + k0, laA[j]);
            load_lds16(pbB[j] + k0, lbB[j]);
        }
        __syncthreads();
#pragma unroll
        for (int h = 0; h < 2; h++) {
            bf16x8 af[4], bfr[4];
#pragma unroll
            for (int mi = 0; mi < 4; mi++)
                af[mi] = *reinterpret_cast<const bf16x8*>(reinterpret_cast<const char*>(lds_a) + aoff[h][mi]);
#pragma unroll
            for (int ni = 0; ni < 4; ni++)
                bfr[ni] = *reinterpret_cast<const bf16x8*>(reinterpret_cast<const char*>(lds_b) + boff[h][ni]);
#pragma unroll
            for (int mi = 0; mi < 4; mi++)
#pragma unroll
                for (int ni = 0; ni < 4; ni++)
                    acc[mi][ni] = __builtin_amdgcn_mfma_f32_16x16x32_bf16(af[mi], bfr[ni], acc[mi][ni], 0, 0, 0);
        }
        __syncthreads();
    }

    float bval[4];
#pragma unroll
    for (int ni = 0; ni < 4; ni++) bval[ni] = bo[nblk + wave_n + ni * 16 + c];
#pragma unroll
    for (int mi = 0; mi < 4; mi++)
#pragma unroll
        for (int ni = 0; ni < 4; ni++) {
            int n = nblk + wave_n + ni * 16 + c;
#pragma unroll
            for (int r = 0; r < 4; r++) {
                int m = mblk + wave_m + mi * 16 + g * 4 + r;
                out[(size_t)m * D_MODEL + n] = acc[mi][ni][r] + bval[ni];
            }
        }
}

extern "C" void kernel_launch(void* const* d_in, const int* in_sizes, int n_in,
                              void* d_out, int out_size, void* d_ws, size_t ws_size,
                              hipStream_t stream) {
    const float* x    = (const float*)d_in[0];
    const int*   mask = (const int*)d_in[1];
    const float* Wq = (const float*)d_in[2];
    const float* bq = (const float*)d_in[3];
    const float* Wk = (const float*)d_in[4];
    const float* bk = (const float*)d_in[5];
    const float* Wv = (const float*)d_in[6];
    const float* bv = (const float*)d_in[7];
    const float* Wo = (const float*)d_in[8];
    const float* bo = (const float*)d_in[9];
    float* out = (float*)d_out;

    char* ws = (char*)d_ws;
    const size_t MB = 1024 * 1024;
    unsigned short* wt  = (unsigned short*)(ws + 0 * MB);
    unsigned short* xb  = (unsigned short*)(ws + 8 * MB);
    unsigned short* qb  = (unsigned short*)(ws + 24 * MB);
    unsigned short* kb  = (unsigned short*)(ws + 40 * MB);
    unsigned short* vt  = (unsigned short*)(ws + 56 * MB);
    unsigned short* ctx = (unsigned short*)(ws + 72 * MB);
    unsigned long long* mb = (unsigned long long*)(ws + 88 * MB);

    wprep<<<dim3(16, 16, 4), 256, 0, stream>>>(Wq, Wk, Wv, Wo, wt);
    xprep<<<dim3(MROWS * D_MODEL / 4 / 256), 256, 0, stream>>>((const float4*)x, xb);
    mprep<<<dim3(MROWS), 256, 0, stream>>>(mask, mb);
    qkv_gemm<<<dim3(1536), 256, 0, stream>>>(xb, wt, bq, bk, bv, qb, kb, vt);
    attn<<<dim3(1024), 128, 0, stream>>>(qb, kb, vt, mb, ctx);
    oproj<<<dim3(512), 256, 0, stream>>>(ctx, wt, bo, out);
}